// Round 6
// baseline (225.849 us; speedup 1.0000x reference)
//
#include <hip/hip_runtime.h>
#include <hip/hip_bf16.h>

// L=2048, E=512, E_PT=300, H=16. All inputs f32. Output f32 [2048,512].
//
// R23 = R22 (proven 204.5us) restructured from 10 -> 6 dispatches:
//  - R22 post-mortem: gram pipeline depth gave only -6% (latency theory
//    falsified); wall ledger shows ~90us of inter-dispatch overhead
//    (~9-10us each, confirmed by R17->R18's +16us for one added combiner).
//    Attack dispatch count, not gram's inner loop.
//  - prep_kernel: compute_y (i8 per-row quant) + label cast + W0/W1
//    transpose in one 6656-block launch (all independent input-only jobs).
//  - gram_i8 keeps R22's proven depth-3/counted-vmcnt body; its 496 dead
//    below-diagonal blocks now host 256 RIDER blocks running the proven
//    T0t = W0t*Lbf^T bf16 GEMM (same 32KB LDS, aliased) -> T0t dispatch
//    eliminated and its ~6us hidden under gram's 50us.
//  - post absorbs scan_repair: row -> LDS (8KB), queue |v-0.1|<3e-3 over
//    the FULL row (no mirror writes: row j repairs (j,i) itself with the
//    bitwise-identical computation), exact-f32 repair via W4 LDS table,
//    softmax straight from LDS. S is never re-read; scan dispatch gone.
//  - adj GEMMs un-split with fused ReLU+bf16/f32 epilogues -> both
//    combiners gone. Split-sum rounding delta << bf16 rounding.
// Dispatches: prep -> gram(+rider) -> post -> adjG1 -> T1t -> adjG2.

typedef __attribute__((ext_vector_type(8))) short bf16x8;
typedef __attribute__((ext_vector_type(4))) float f32x4;
typedef __attribute__((ext_vector_type(4))) int i32x4;

#define L_DIM 2048
#define EPT 300
#define H_DIM 16
#define KDIM 4800
#define WINDOW 3.0e-3f  // two-sided borderline window (~18 sigma at typ rowmax)

// ------- 1) prep: Y(i8 per-row) + norms + inv_s  |  label cast  |  W^T ------
// grid 6656: [0,2048) y-rows; [2048,6144) label cast; [6144,6656) transpose.
__global__ __launch_bounds__(256) void prep_kernel(const float* __restrict__ xpt,
                                                   const float* __restrict__ Wpt,
                                                   const float* __restrict__ label,
                                                   const float* __restrict__ W0,
                                                   const float* __restrict__ W1,
                                                   signed char* __restrict__ Y,
                                                   float* __restrict__ norms,
                                                   float* __restrict__ inv_s,
                                                   __hip_bfloat16* __restrict__ Lbf,
                                                   __hip_bfloat16* __restrict__ W0t,
                                                   __hip_bfloat16* __restrict__ W1t) {
  __shared__ float redmax[4];
  __shared__ float tile[32][33];
  const int b = blockIdx.x;
  const int tid = threadIdx.x;
  if (b < 2048) {
    const int i = b;  // row
    const int lane = tid & 63;
    const int w = tid >> 6;  // wave 0..3 -> heads 4w..4w+3
    const float* x = xpt + i * EPT;
    float y[4][5];
    float wmax = 0.f;
#pragma unroll
    for (int hh = 0; hh < 4; ++hh) {
      const int h = w * 4 + hh;
      const float* wp = Wpt + h * EPT;
      float ss = 0.f;
#pragma unroll
      for (int t = 0; t < 5; ++t) {
        int e = lane + 64 * t;
        float val = 0.f;
        if (e < EPT) {
          float we = wp[e];
          val = x[e] * we * we;
        }
        y[hh][t] = val;
        ss += val * val;
      }
#pragma unroll
      for (int o = 32; o >= 1; o >>= 1) ss += __shfl_xor(ss, o, 64);
      float n = fmaxf(sqrtf(ss), 1e-12f);
      if (lane == 0) norms[i * H_DIM + h] = n;
      float scale = 0.25f / n;  // per-head y = v/(norm*sqrt(H)); |y| <= 0.25
#pragma unroll
      for (int t = 0; t < 5; ++t) {
        y[hh][t] *= scale;
        wmax = fmaxf(wmax, fabsf(y[hh][t]));
      }
    }
#pragma unroll
    for (int o = 32; o >= 1; o >>= 1) wmax = fmaxf(wmax, __shfl_xor(wmax, o, 64));
    if (lane == 0) redmax[w] = wmax;
    __syncthreads();
    float rowmax = fmaxf(fmaxf(redmax[0], redmax[1]), fmaxf(redmax[2], redmax[3]));
    rowmax = fmaxf(rowmax, 1e-12f);
    const float qs = 127.0f / rowmax;
    if (tid == 0) inv_s[i] = rowmax * (1.0f / 127.0f);
#pragma unroll
    for (int hh = 0; hh < 4; ++hh) {
      const int h = w * 4 + hh;
#pragma unroll
      for (int t = 0; t < 5; ++t) {
        int e = lane + 64 * t;
        if (e < EPT) {
          int qv = __float2int_rn(y[hh][t] * qs);
          qv = max(-127, min(127, qv));
          Y[(size_t)i * KDIM + h * EPT + e] = (signed char)qv;
        }
      }
    }
    return;
  }
  if (b < 6144) {
    int i = (b - 2048) * 256 + tid;
    Lbf[i] = __float2bfloat16(label[i]);
    return;
  }
  int local = b - 6144;
  const bool first = local < 256;
  const float* src = first ? W0 : W1;
  __hip_bfloat16* dst = first ? W0t : W1t;
  int rem = local & 255;
  int c0 = (rem & 15) * 32, r0 = (rem >> 4) * 32;
  int tx = tid & 31, ty = tid >> 5;
  for (int i2 = ty; i2 < 32; i2 += 8) tile[i2][tx] = src[(size_t)(r0 + i2) * 512 + c0 + tx];
  __syncthreads();
  for (int i2 = ty; i2 < 32; i2 += 8)
    dst[(size_t)(c0 + i2) * 512 + r0 + tx] = __float2bfloat16(tile[tx][i2]);
}

// ---------------- 2) int8 gram (R22-proven) + T0t RIDER on dead blocks ------
// Live blocks (col>=row tile): 64x64 i8 gram, depth-3 prefetch, counted
// vmcnt, raw barriers. Dead blocks (496): first 256 run T0t = W0t*Lbf^T
// bf16 GEMM tiles (proven gemm_bt body, BM=BN=64, K=512, OUT_BF16).
__global__ __launch_bounds__(256) void gram_i8(const signed char* __restrict__ Y,
                                               float* __restrict__ S,
                                               const float* __restrict__ inv_s,
                                               const __hip_bfloat16* __restrict__ W0t,
                                               const __hip_bfloat16* __restrict__ Lbf,
                                               __hip_bfloat16* __restrict__ T0t) {
  __shared__ __attribute__((aligned(16))) char smem[32768];
  // XCD-locality remap: XCD k (id%8) owns col-tiles {k, k+8, k+16, k+24}
  const int id = blockIdx.x;
  const int bx = (id & 7) | (((id >> 3) & 3) << 3);
  const int by = id >> 5;
  const int row0 = by * 64, col0 = bx * 64;
  const int tid = threadIdx.x;
  const int lane = tid & 63;
  const int wn = tid >> 6;
  const int r = lane & 15, q = lane >> 4;

  if (col0 + 64 <= row0) {
    // ---- RIDER: T0t tile GEMM (dead gram slot) ----
    const int d = (by * (by - 1)) / 2 + bx;  // 0..495 (bx < by)
    if (d >= 256) return;
    const int row0r = (d >> 5) * 64;  // [0,512)
    const int col0r = (d & 31) * 64;  // [0,2048)
    __hip_bfloat16* Asb = (__hip_bfloat16*)smem;             // [2][4096] bf16
    __hip_bfloat16* Bsb = (__hip_bfloat16*)(smem + 16384);   // [2][4096] bf16
    const int srow8 = tid >> 3;
    const int schunk8 = (tid & 7) ^ (srow8 & 7);
    f32x4 racc[4];
#pragma unroll
    for (int t = 0; t < 4; ++t) {
      f32x4 z = {0.f, 0.f, 0.f, 0.f};
      racc[t] = z;
    }
#define RSTAGE(bufi, k0)                                                                      \
  {                                                                                           \
    _Pragma("unroll") for (int it = 0; it < 2; ++it) {                                        \
      __builtin_amdgcn_global_load_lds(                                                       \
          (const __attribute__((address_space(1))) void*)(W0t + (size_t)(row0r + it * 32 + srow8) * 512 + \
                                                          (k0) + schunk8 * 8),                \
          (__attribute__((address_space(3))) void*)(Asb + (bufi)*4096 + (it * 256 + tid) * 8), 16, 0, 0); \
    }                                                                                         \
    _Pragma("unroll") for (int it = 0; it < 2; ++it) {                                        \
      __builtin_amdgcn_global_load_lds(                                                       \
          (const __attribute__((address_space(1))) void*)(Lbf + (size_t)(col0r + it * 32 + srow8) * 512 + \
                                                          (k0) + schunk8 * 8),                \
          (__attribute__((address_space(3))) void*)(Bsb + (bufi)*4096 + (it * 256 + tid) * 8), 16, 0, 0); \
    }                                                                                         \
  }
    RSTAGE(0, 0)
    for (int k = 0; k < 8; ++k) {
      __syncthreads();
      if (k + 1 < 8) RSTAGE((k + 1) & 1, (k + 1) * 64)
      const __hip_bfloat16* as = Asb + (k & 1) * 4096;
      const __hip_bfloat16* bs = Bsb + (k & 1) * 4096;
#pragma unroll
      for (int kk = 0; kk < 2; ++kk) {
        const int ch = ((kk * 4 + q) ^ (r & 7)) * 8;
        bf16x8 af[4];
#pragma unroll
        for (int t = 0; t < 4; ++t) af[t] = *(const bf16x8*)(as + (t * 16 + r) * 64 + ch);
        bf16x8 bfr = *(const bf16x8*)(bs + (wn * 16 + r) * 64 + ch);
#pragma unroll
        for (int t = 0; t < 4; ++t)
          racc[t] = __builtin_amdgcn_mfma_f32_16x16x32_bf16(af[t], bfr, racc[t], 0, 0, 0);
      }
    }
#undef RSTAGE
    const int gcr = col0r + wn * 16 + r;
#pragma unroll
    for (int t = 0; t < 4; ++t) {
      int gr0 = row0r + t * 16 + q * 4;
#pragma unroll
      for (int p = 0; p < 4; ++p)
        T0t[(size_t)(gr0 + p) * 2048 + gcr] = __float2bfloat16(racc[t][p]);
    }
    return;
  }

  // ---- gram main path (R22 verbatim, smem flattened) ----
  const bool do_mirror = (col0 > row0);
  signed char* As = (signed char*)smem;           // [4][4096] i8
  signed char* Bs = (signed char*)(smem + 16384); // [4][4096] i8
  const int srow = tid >> 2;                     // staging row 0..63
  const int sc = (tid & 3) ^ ((srow >> 2) & 3);  // global 16B chunk for this slot

  i32x4 acc[4];
#pragma unroll
  for (int t = 0; t < 4; ++t) {
    i32x4 z = {0, 0, 0, 0};
    acc[t] = z;
  }
  const int niter = KDIM / 64;  // 75

#define STAGEI(bufi, k0)                                                                       \
  {                                                                                            \
    __builtin_amdgcn_global_load_lds(                                                          \
        (const __attribute__((address_space(1))) void*)(Y + (size_t)(row0 + srow) * KDIM +     \
                                                        (k0) + sc * 16),                       \
        (__attribute__((address_space(3))) void*)(As + (bufi)*4096 + tid * 16), 16, 0, 0);     \
    __builtin_amdgcn_global_load_lds(                                                          \
        (const __attribute__((address_space(1))) void*)(Y + (size_t)(col0 + srow) * KDIM +     \
                                                        (k0) + sc * 16),                       \
        (__attribute__((address_space(3))) void*)(Bs + (bufi)*4096 + tid * 16), 16, 0, 0);     \
  }

  auto compute = [&](int bufi) {
    const signed char* as = As + bufi * 4096;
    const signed char* bs = Bs + bufi * 4096;
    const int ch = (q ^ ((r >> 2) & 3)) * 16;  // swizzled 16B chunk
    i32x4 bfrag = *(const i32x4*)(bs + (wn * 16 + r) * 64 + ch);
#pragma unroll
    for (int t = 0; t < 4; ++t) {
      i32x4 afrag = *(const i32x4*)(as + (t * 16 + r) * 64 + ch);
      acc[t] = __builtin_amdgcn_mfma_i32_16x16x64_i8(afrag, bfrag, acc[t], 0, 0, 0);
    }
  };

  STAGEI(0, 0)
  STAGEI(1, 64)
  STAGEI(2, 128)
  for (int k = 0; k < niter - 3; ++k) {
    asm volatile("s_waitcnt vmcnt(4)" ::: "memory");
    __builtin_amdgcn_s_barrier();
    __builtin_amdgcn_sched_barrier(0);
    STAGEI((k + 3) & 3, (k + 3) * 64)
    compute(k & 3);
  }
  asm volatile("s_waitcnt vmcnt(4)" ::: "memory");
  __builtin_amdgcn_s_barrier();
  __builtin_amdgcn_sched_barrier(0);
  compute((niter - 3) & 3);
  asm volatile("s_waitcnt vmcnt(2)" ::: "memory");
  __builtin_amdgcn_s_barrier();
  __builtin_amdgcn_sched_barrier(0);
  compute((niter - 2) & 3);
  asm volatile("s_waitcnt vmcnt(0)" ::: "memory");
  __builtin_amdgcn_s_barrier();
  __builtin_amdgcn_sched_barrier(0);
  compute((niter - 1) & 3);
#undef STAGEI
  // C/D layout: col = lane&15, row = (lane>>4)*4 + reg (shape-determined)
  const int gc = col0 + wn * 16 + r;
  const float sj = inv_s[gc];
#pragma unroll
  for (int t = 0; t < 4; ++t) {
    int gr0 = row0 + t * 16 + q * 4;
#pragma unroll
    for (int p = 0; p < 4; ++p) {
      float vv = (float)acc[t][p] * (inv_s[gr0 + p] * sj);
      S[(size_t)(gr0 + p) * L_DIM + gc] = vv;
      if (do_mirror) S[(size_t)gc * L_DIM + (gr0 + p)] = vv;
    }
  }
}

// ---------------- 2b) bf16 bt-GEMM (R17-proven, BK=64) ----------------
template <int BM, int BN, bool RELU, bool OUT_BF16>
__global__ __launch_bounds__(256) void gemm_bt(const __hip_bfloat16* __restrict__ A,
                                               const __hip_bfloat16* __restrict__ B,
                                               void* __restrict__ C0v,
                                               int M, int N, int K) {
  constexpr int WMG = BM / 64;
  constexpr int WNG = 4 / WMG;
  constexpr int NC = BN / (16 * WNG);
  const int row0 = blockIdx.y * BM, col0 = blockIdx.x * BN;
  __shared__ __attribute__((aligned(16))) __hip_bfloat16 As[2][BM * 64];
  __shared__ __attribute__((aligned(16))) __hip_bfloat16 Bs[2][BN * 64];
  const int tid = threadIdx.x;
  const int lane = tid & 63;
  const int wave = tid >> 6;
  const int wm = wave / WNG, wn = wave % WNG;
  const int r = lane & 15, q = lane >> 4;
  const int srow = tid >> 3;
  const int schunk = (tid & 7) ^ (srow & 7);

  f32x4 acc[4][NC];
#pragma unroll
  for (int a = 0; a < 4; ++a)
#pragma unroll
    for (int b = 0; b < NC; ++b) {
      f32x4 z = {0.f, 0.f, 0.f, 0.f};
      acc[a][b] = z;
    }

  const int niter = K >> 6;

#define STAGE(bufi, k0)                                                                       \
  {                                                                                           \
    _Pragma("unroll") for (int it = 0; it < BM / 32; ++it) {                                  \
      __builtin_amdgcn_global_load_lds(                                                       \
          (const __attribute__((address_space(1))) void*)(A + (size_t)(row0 + it * 32 + srow) * K + \
                                                          (k0) + schunk * 8),                 \
          (__attribute__((address_space(3))) void*)(&As[bufi][(it * 256 + tid) * 8]), 16, 0, 0); \
    }                                                                                         \
    _Pragma("unroll") for (int it = 0; it < BN / 32; ++it) {                                  \
      __builtin_amdgcn_global_load_lds(                                                       \
          (const __attribute__((address_space(1))) void*)(B + (size_t)(col0 + it * 32 + srow) * K + \
                                                          (k0) + schunk * 8),                 \
          (__attribute__((address_space(3))) void*)(&Bs[bufi][(it * 256 + tid) * 8]), 16, 0, 0); \
    }                                                                                         \
  }

  STAGE(0, 0)
  for (int k = 0; k < niter; ++k) {
    __syncthreads();
    if (k + 1 < niter) STAGE((k + 1) & 1, (k + 1) << 6)
    const __hip_bfloat16* as = As[k & 1];
    const __hip_bfloat16* bs = Bs[k & 1];
#pragma unroll
    for (int kk = 0; kk < 2; ++kk) {
      const int ch = ((kk * 4 + q) ^ (r & 7)) * 8;
      bf16x8 af[4], bfr[NC];
#pragma unroll
      for (int t = 0; t < 4; ++t)
        af[t] = *(const bf16x8*)(as + (wm * 64 + t * 16 + r) * 64 + ch);
#pragma unroll
      for (int c = 0; c < NC; ++c)
        bfr[c] = *(const bf16x8*)(bs + (wn * 16 * NC + c * 16 + r) * 64 + ch);
#pragma unroll
      for (int tm = 0; tm < 4; ++tm)
#pragma unroll
        for (int tn = 0; tn < NC; ++tn)
          acc[tm][tn] = __builtin_amdgcn_mfma_f32_16x16x32_bf16(af[tm], bfr[tn], acc[tm][tn], 0, 0, 0);
    }
  }
#undef STAGE
  // C/D layout: col = lane&15, row = (lane>>4)*4 + reg   [guide §3, m89-verified]
#pragma unroll
  for (int tm = 0; tm < 4; ++tm) {
    int gr0 = row0 + wm * 64 + tm * 16 + q * 4;
#pragma unroll
    for (int tn = 0; tn < NC; ++tn) {
      int gc = col0 + wn * 16 * NC + tn * 16 + r;
#pragma unroll
      for (int p = 0; p < 4; ++p) {
        float vv = acc[tm][tn][p];
        if (RELU) vv = fmaxf(vv, 0.f);
        if (OUT_BF16) {
          ((__hip_bfloat16*)C0v)[(size_t)(gr0 + p) * N + gc] = __float2bfloat16(vv);
        } else {
          ((float*)C0v)[(size_t)(gr0 + p) * N + gc] = vv;
        }
      }
    }
  }
}

// ------- 3) post: row->LDS, borderline repair in-LDS, softmax -> adj --------
__global__ __launch_bounds__(256) void post_kernel(const float* __restrict__ S,
                                                   __hip_bfloat16* __restrict__ adj,
                                                   const float* __restrict__ xpt,
                                                   const float* __restrict__ Wpt,
                                                   const float* __restrict__ norms) {
  __shared__ float rowv[L_DIM];  // 8KB: this row of S
  __shared__ float W4[KDIM];     // 19.2KB: w^4 table (built only if queue non-empty)
  __shared__ int lq[2048];
  __shared__ int lcount;
  __shared__ float red[4];
  const int b = blockIdx.x;
  const int tid = threadIdx.x;
  if (tid == 0) lcount = 0;
  __syncthreads();
  const float* s = S + (size_t)b * L_DIM;
  // load row into LDS + queue borderline entries (FULL row — no mirrors needed;
  // row j repairs (j,i) itself with the bitwise-identical computation)
  for (int j0 = tid * 4; j0 < L_DIM; j0 += 1024) {
    float4 v = *(const float4*)(s + j0);
    *(float4*)(&rowv[j0]) = v;
    float vv[4] = {v.x, v.y, v.z, v.w};
#pragma unroll
    for (int u = 0; u < 4; ++u) {
      if (fabsf(vv[u] - 0.1f) < WINDOW) {
        int p = atomicAdd(&lcount, 1);
        lq[p] = j0 + u;
      }
    }
  }
  __syncthreads();
  const int n = lcount;
  if (n > 0) {
    for (int e = tid; e < KDIM; e += 256) {
      float w = Wpt[e];
      float w2 = w * w;
      W4[e] = w2 * w2;
    }
    __syncthreads();
    const int lane = tid & 63;
    const int wave = tid >> 6;
    float xiv[5];
    {
      const float* xi = xpt + b * EPT;
#pragma unroll
      for (int t = 0; t < 5; ++t) {
        int idx = lane + 64 * t;
        xiv[t] = idx < EPT ? xi[idx] : 0.f;
      }
    }
    for (int k = wave; k < n; k += 4) {
      int j = lq[k];
      const float* xj = xpt + j * EPT;
      float pre[5];
#pragma unroll
      for (int t = 0; t < 5; ++t) {
        int idx = lane + 64 * t;
        pre[t] = idx < EPT ? xiv[t] * xj[idx] : 0.f;
      }
      float accv = 0.f;
#pragma unroll
      for (int h = 0; h < H_DIM; ++h) {
        float ph = 0.f;
#pragma unroll
        for (int t = 0; t < 5; ++t) {
          int idx = lane + 64 * t;
          if (idx < EPT) ph += pre[t] * W4[h * EPT + idx];
        }
        accv += ph * (1.f / (norms[b * H_DIM + h] * norms[j * H_DIM + h]));
      }
#pragma unroll
      for (int o = 32; o >= 1; o >>= 1) accv += __shfl_xor(accv, o, 64);
      if (lane == 0) rowv[j] = accv * (1.f / 16.f);
    }
    __syncthreads();
  }
  // softmax from LDS (same math as proven post)
  float m = -1e30f;
  for (int j = tid; j < L_DIM; j += 256) {
    float v = rowv[j];
    if (v >= 0.1f && v > m) m = v;
  }
#pragma unroll
  for (int o = 32; o >= 1; o >>= 1) m = fmaxf(m, __shfl_xor(m, o, 64));
  if ((tid & 63) == 0) red[tid >> 6] = m;
  __syncthreads();
  m = fmaxf(fmaxf(red[0], red[1]), fmaxf(red[2], red[3]));
  float sum = 0.f;
  for (int j = tid; j < L_DIM; j += 256) {
    float v = rowv[j];
    if (v >= 0.1f) sum += __expf(v - m);
  }
#pragma unroll
  for (int o = 32; o >= 1; o >>= 1) sum += __shfl_xor(sum, o, 64);
  __syncthreads();
  if ((tid & 63) == 0) red[tid >> 6] = sum;
  __syncthreads();
  sum = red[0] + red[1] + red[2] + red[3];
  float inv = 1.f / sum;
  for (int j = tid; j < L_DIM; j += 256) {
    float v = rowv[j];
    float a = (v >= 0.1f) ? __expf(v - m) * inv : 0.f;
    adj[(size_t)b * L_DIM + j] = __float2bfloat16(a);
  }
}

extern "C" void kernel_launch(void* const* d_in, const int* in_sizes, int n_in, void* d_out,
                              int out_size, void* d_ws, size_t ws_size, hipStream_t stream) {
  const float* label = (const float*)d_in[0];  // [2048,512]
  const float* xpt = (const float*)d_in[1];    // [2048,300]
  const float* Wpt = (const float*)d_in[2];    // [16,300]
  const float* W0 = (const float*)d_in[3];     // [512,512]
  const float* W1 = (const float*)d_in[4];     // [512,512]
  float* out = (float*)d_out;                  // [2048,512]

  // ---- layout (peak 47.1MB; ws >= 53.4MB proven) ----
  char* ws = (char*)d_ws;
  signed char* Y = (signed char*)ws;                    // [0, 9,830,400) live thru gram
  float* S = (float*)(ws + 19660800);                   // [19,660,800, 36,438,016)
  float* norms = (float*)(ws + 36438016);               // 128KB -> ends 36,569,088
  float* inv_s = (float*)(ws + 44957696);               // 8KB -> ends 44,965,888
  __hip_bfloat16* Lbf = (__hip_bfloat16*)(ws + 44965888);  // 2MB -> ends 47,063,040
  __hip_bfloat16* adj = (__hip_bfloat16*)ws;            // [0, 8,388,608) after post (Y dead)
  // GCN temporaries above Y's region (disjoint from Y [0,9.83M)):
  __hip_bfloat16* W0t = (__hip_bfloat16*)(ws + 10485760);   // 0.5MB
  __hip_bfloat16* W1t = (__hip_bfloat16*)(ws + 11010048);   // 0.5MB
  __hip_bfloat16* T0t = (__hip_bfloat16*)(ws + 11534336);   // 2MB [512x2048]
  __hip_bfloat16* X1 = (__hip_bfloat16*)(ws + 13631488);    // 2MB [2048x512]
  __hip_bfloat16* T1t = (__hip_bfloat16*)(ws + 15728640);   // 2MB -> ends 17,825,792

  // 1) Y-quant rows + label cast + W0/W1 transposes (one launch)
  prep_kernel<<<6656, 256, 0, stream>>>(xpt, Wpt, label, W0, W1, Y, norms, inv_s, Lbf, W0t, W1t);
  // 2) gram (triangle+mirror, XCD-swizzled, depth-3 counted-vmcnt) + T0t rider
  gram_i8<<<1024, 256, 0, stream>>>(Y, S, inv_s, W0t, Lbf, T0t);
  // 3) in-LDS borderline repair + softmax -> adj
  post_kernel<<<2048, 256, 0, stream>>>(S, adj, xpt, Wpt, norms);
  // 4) X1 = relu_bf16(adj @ T0t^T)
  gemm_bt<64, 64, true, true><<<dim3(8, 32), 256, 0, stream>>>(adj, T0t, X1, 2048, 512, 2048);
  // 5) T1t = bf16(W1t @ X1^T)   [512 x 2048]
  gemm_bt<64, 64, false, true><<<dim3(32, 8), 256, 0, stream>>>(W1t, X1, T1t, 512, 2048, 512);
  // 6) out = relu_f32(adj @ T1t^T)
  gemm_bt<64, 64, true, false><<<dim3(8, 32), 256, 0, stream>>>(adj, T1t, out, 2048, 512, 2048);
}

// Round 7
// 204.830 us; speedup vs baseline: 1.1026x; 1.1026x over previous
//
#include <hip/hip_runtime.h>
#include <hip/hip_bf16.h>

// L=2048, E=512, E_PT=300, H=16. All inputs f32. Output f32 [2048,512].
//
// R24 = best-of(R22, R23):
//  - R23 post-mortem: post_kernel = 60us, VALUBusy 56% => repair loop
//    dominates (n~65/row at 3e-3 window); un-split adj GEMMs regressed
//    (~23us each at 1 block/CU); prep merge + T0t rider validated.
//  - Keep: prep merge, gram_i8 depth-3 counted-vmcnt + T0t rider, merged
//    post (S read once into LDS, repair, softmax from LDS).
//  - Fix 1: WINDOW 3e-3 -> 1.5e-3 (= 8 sigma of the 1.8e-4 i8 score error;
//    P(misclassification) ~1e-10 over 2M entries). Repair work halves.
//    Hoist 1/norm_i per row; lq 2048->1024 (LDS 35.8->31.5KB, 5 blocks/CU).
//  - Fix 2: restore R22-proven split-K=2 adj GEMMs + combiners
//    (11+4us vs 23us un-split).
// Dispatches (8): prep -> gram(+T0t rider) -> post -> adjG1 -> combine_bf16
//                 -> T1t -> adjG2 -> combine_f32.

typedef __attribute__((ext_vector_type(8))) short bf16x8;
typedef __attribute__((ext_vector_type(4))) float f32x4;
typedef __attribute__((ext_vector_type(4))) int i32x4;

#define L_DIM 2048
#define EPT 300
#define H_DIM 16
#define KDIM 4800
#define WINDOW 1.5e-3f  // two-sided borderline window (~8 sigma of i8 error)

// ------- 1) prep: Y(i8 per-row) + norms + inv_s  |  label cast  |  W^T ------
// grid 6656: [0,2048) y-rows; [2048,6144) label cast; [6144,6656) transpose.
__global__ __launch_bounds__(256) void prep_kernel(const float* __restrict__ xpt,
                                                   const float* __restrict__ Wpt,
                                                   const float* __restrict__ label,
                                                   const float* __restrict__ W0,
                                                   const float* __restrict__ W1,
                                                   signed char* __restrict__ Y,
                                                   float* __restrict__ norms,
                                                   float* __restrict__ inv_s,
                                                   __hip_bfloat16* __restrict__ Lbf,
                                                   __hip_bfloat16* __restrict__ W0t,
                                                   __hip_bfloat16* __restrict__ W1t) {
  __shared__ float redmax[4];
  __shared__ float tile[32][33];
  const int b = blockIdx.x;
  const int tid = threadIdx.x;
  if (b < 2048) {
    const int i = b;  // row
    const int lane = tid & 63;
    const int w = tid >> 6;  // wave 0..3 -> heads 4w..4w+3
    const float* x = xpt + i * EPT;
    float y[4][5];
    float wmax = 0.f;
#pragma unroll
    for (int hh = 0; hh < 4; ++hh) {
      const int h = w * 4 + hh;
      const float* wp = Wpt + h * EPT;
      float ss = 0.f;
#pragma unroll
      for (int t = 0; t < 5; ++t) {
        int e = lane + 64 * t;
        float val = 0.f;
        if (e < EPT) {
          float we = wp[e];
          val = x[e] * we * we;
        }
        y[hh][t] = val;
        ss += val * val;
      }
#pragma unroll
      for (int o = 32; o >= 1; o >>= 1) ss += __shfl_xor(ss, o, 64);
      float n = fmaxf(sqrtf(ss), 1e-12f);
      if (lane == 0) norms[i * H_DIM + h] = n;
      float scale = 0.25f / n;  // per-head y = v/(norm*sqrt(H)); |y| <= 0.25
#pragma unroll
      for (int t = 0; t < 5; ++t) {
        y[hh][t] *= scale;
        wmax = fmaxf(wmax, fabsf(y[hh][t]));
      }
    }
#pragma unroll
    for (int o = 32; o >= 1; o >>= 1) wmax = fmaxf(wmax, __shfl_xor(wmax, o, 64));
    if (lane == 0) redmax[w] = wmax;
    __syncthreads();
    float rowmax = fmaxf(fmaxf(redmax[0], redmax[1]), fmaxf(redmax[2], redmax[3]));
    rowmax = fmaxf(rowmax, 1e-12f);
    const float qs = 127.0f / rowmax;
    if (tid == 0) inv_s[i] = rowmax * (1.0f / 127.0f);
#pragma unroll
    for (int hh = 0; hh < 4; ++hh) {
      const int h = w * 4 + hh;
#pragma unroll
      for (int t = 0; t < 5; ++t) {
        int e = lane + 64 * t;
        if (e < EPT) {
          int qv = __float2int_rn(y[hh][t] * qs);
          qv = max(-127, min(127, qv));
          Y[(size_t)i * KDIM + h * EPT + e] = (signed char)qv;
        }
      }
    }
    return;
  }
  if (b < 6144) {
    int i = (b - 2048) * 256 + tid;
    Lbf[i] = __float2bfloat16(label[i]);
    return;
  }
  int local = b - 6144;
  const bool first = local < 256;
  const float* src = first ? W0 : W1;
  __hip_bfloat16* dst = first ? W0t : W1t;
  int rem = local & 255;
  int c0 = (rem & 15) * 32, r0 = (rem >> 4) * 32;
  int tx = tid & 31, ty = tid >> 5;
  for (int i2 = ty; i2 < 32; i2 += 8) tile[i2][tx] = src[(size_t)(r0 + i2) * 512 + c0 + tx];
  __syncthreads();
  for (int i2 = ty; i2 < 32; i2 += 8)
    dst[(size_t)(c0 + i2) * 512 + r0 + tx] = __float2bfloat16(tile[tx][i2]);
}

// ---------------- 2) int8 gram (R22-proven) + T0t RIDER on dead blocks ------
__global__ __launch_bounds__(256) void gram_i8(const signed char* __restrict__ Y,
                                               float* __restrict__ S,
                                               const float* __restrict__ inv_s,
                                               const __hip_bfloat16* __restrict__ W0t,
                                               const __hip_bfloat16* __restrict__ Lbf,
                                               __hip_bfloat16* __restrict__ T0t) {
  __shared__ __attribute__((aligned(16))) char smem[32768];
  // XCD-locality remap: XCD k (id%8) owns col-tiles {k, k+8, k+16, k+24}
  const int id = blockIdx.x;
  const int bx = (id & 7) | (((id >> 3) & 3) << 3);
  const int by = id >> 5;
  const int row0 = by * 64, col0 = bx * 64;
  const int tid = threadIdx.x;
  const int lane = tid & 63;
  const int wn = tid >> 6;
  const int r = lane & 15, q = lane >> 4;

  if (col0 + 64 <= row0) {
    // ---- RIDER: T0t tile GEMM (dead gram slot), R23-proven ----
    const int d = (by * (by - 1)) / 2 + bx;  // 0..495 (bx < by)
    if (d >= 256) return;
    const int row0r = (d >> 5) * 64;  // [0,512)
    const int col0r = (d & 31) * 64;  // [0,2048)
    __hip_bfloat16* Asb = (__hip_bfloat16*)smem;             // [2][4096] bf16
    __hip_bfloat16* Bsb = (__hip_bfloat16*)(smem + 16384);   // [2][4096] bf16
    const int srow8 = tid >> 3;
    const int schunk8 = (tid & 7) ^ (srow8 & 7);
    f32x4 racc[4];
#pragma unroll
    for (int t = 0; t < 4; ++t) {
      f32x4 z = {0.f, 0.f, 0.f, 0.f};
      racc[t] = z;
    }
#define RSTAGE(bufi, k0)                                                                      \
  {                                                                                           \
    _Pragma("unroll") for (int it = 0; it < 2; ++it) {                                        \
      __builtin_amdgcn_global_load_lds(                                                       \
          (const __attribute__((address_space(1))) void*)(W0t + (size_t)(row0r + it * 32 + srow8) * 512 + \
                                                          (k0) + schunk8 * 8),                \
          (__attribute__((address_space(3))) void*)(Asb + (bufi)*4096 + (it * 256 + tid) * 8), 16, 0, 0); \
    }                                                                                         \
    _Pragma("unroll") for (int it = 0; it < 2; ++it) {                                        \
      __builtin_amdgcn_global_load_lds(                                                       \
          (const __attribute__((address_space(1))) void*)(Lbf + (size_t)(col0r + it * 32 + srow8) * 512 + \
                                                          (k0) + schunk8 * 8),                \
          (__attribute__((address_space(3))) void*)(Bsb + (bufi)*4096 + (it * 256 + tid) * 8), 16, 0, 0); \
    }                                                                                         \
  }
    RSTAGE(0, 0)
    for (int k = 0; k < 8; ++k) {
      __syncthreads();
      if (k + 1 < 8) RSTAGE((k + 1) & 1, (k + 1) * 64)
      const __hip_bfloat16* as = Asb + (k & 1) * 4096;
      const __hip_bfloat16* bs = Bsb + (k & 1) * 4096;
#pragma unroll
      for (int kk = 0; kk < 2; ++kk) {
        const int ch = ((kk * 4 + q) ^ (r & 7)) * 8;
        bf16x8 af[4];
#pragma unroll
        for (int t = 0; t < 4; ++t) af[t] = *(const bf16x8*)(as + (t * 16 + r) * 64 + ch);
        bf16x8 bfr = *(const bf16x8*)(bs + (wn * 16 + r) * 64 + ch);
#pragma unroll
        for (int t = 0; t < 4; ++t)
          racc[t] = __builtin_amdgcn_mfma_f32_16x16x32_bf16(af[t], bfr, racc[t], 0, 0, 0);
      }
    }
#undef RSTAGE
    const int gcr = col0r + wn * 16 + r;
#pragma unroll
    for (int t = 0; t < 4; ++t) {
      int gr0 = row0r + t * 16 + q * 4;
#pragma unroll
      for (int p = 0; p < 4; ++p)
        T0t[(size_t)(gr0 + p) * 2048 + gcr] = __float2bfloat16(racc[t][p]);
    }
    return;
  }

  // ---- gram main path (R22 verbatim) ----
  const bool do_mirror = (col0 > row0);
  signed char* As = (signed char*)smem;           // [4][4096] i8
  signed char* Bs = (signed char*)(smem + 16384); // [4][4096] i8
  const int srow = tid >> 2;                     // staging row 0..63
  const int sc = (tid & 3) ^ ((srow >> 2) & 3);  // global 16B chunk for this slot

  i32x4 acc[4];
#pragma unroll
  for (int t = 0; t < 4; ++t) {
    i32x4 z = {0, 0, 0, 0};
    acc[t] = z;
  }
  const int niter = KDIM / 64;  // 75

#define STAGEI(bufi, k0)                                                                       \
  {                                                                                            \
    __builtin_amdgcn_global_load_lds(                                                          \
        (const __attribute__((address_space(1))) void*)(Y + (size_t)(row0 + srow) * KDIM +     \
                                                        (k0) + sc * 16),                       \
        (__attribute__((address_space(3))) void*)(As + (bufi)*4096 + tid * 16), 16, 0, 0);     \
    __builtin_amdgcn_global_load_lds(                                                          \
        (const __attribute__((address_space(1))) void*)(Y + (size_t)(col0 + srow) * KDIM +     \
                                                        (k0) + sc * 16),                       \
        (__attribute__((address_space(3))) void*)(Bs + (bufi)*4096 + tid * 16), 16, 0, 0);     \
  }

  auto compute = [&](int bufi) {
    const signed char* as = As + bufi * 4096;
    const signed char* bs = Bs + bufi * 4096;
    const int ch = (q ^ ((r >> 2) & 3)) * 16;  // swizzled 16B chunk
    i32x4 bfrag = *(const i32x4*)(bs + (wn * 16 + r) * 64 + ch);
#pragma unroll
    for (int t = 0; t < 4; ++t) {
      i32x4 afrag = *(const i32x4*)(as + (t * 16 + r) * 64 + ch);
      acc[t] = __builtin_amdgcn_mfma_i32_16x16x64_i8(afrag, bfrag, acc[t], 0, 0, 0);
    }
  };

  STAGEI(0, 0)
  STAGEI(1, 64)
  STAGEI(2, 128)
  for (int k = 0; k < niter - 3; ++k) {
    asm volatile("s_waitcnt vmcnt(4)" ::: "memory");
    __builtin_amdgcn_s_barrier();
    __builtin_amdgcn_sched_barrier(0);
    STAGEI((k + 3) & 3, (k + 3) * 64)
    compute(k & 3);
  }
  asm volatile("s_waitcnt vmcnt(4)" ::: "memory");
  __builtin_amdgcn_s_barrier();
  __builtin_amdgcn_sched_barrier(0);
  compute((niter - 3) & 3);
  asm volatile("s_waitcnt vmcnt(2)" ::: "memory");
  __builtin_amdgcn_s_barrier();
  __builtin_amdgcn_sched_barrier(0);
  compute((niter - 2) & 3);
  asm volatile("s_waitcnt vmcnt(0)" ::: "memory");
  __builtin_amdgcn_s_barrier();
  __builtin_amdgcn_sched_barrier(0);
  compute((niter - 1) & 3);
#undef STAGEI
  // C/D layout: col = lane&15, row = (lane>>4)*4 + reg (shape-determined)
  const int gc = col0 + wn * 16 + r;
  const float sj = inv_s[gc];
#pragma unroll
  for (int t = 0; t < 4; ++t) {
    int gr0 = row0 + t * 16 + q * 4;
#pragma unroll
    for (int p = 0; p < 4; ++p) {
      float vv = (float)acc[t][p] * (inv_s[gr0 + p] * sj);
      S[(size_t)(gr0 + p) * L_DIM + gc] = vv;
      if (do_mirror) S[(size_t)gc * L_DIM + (gr0 + p)] = vv;
    }
  }
}

// ---------------- 2b) bf16 bt-GEMM (R17/R22-proven, BK=64, SPLITX) ----------
template <int BM, int BN, bool RELU, bool OUT_BF16, bool MIRROR, bool SPLITX>
__global__ __launch_bounds__(256) void gemm_bt(const __hip_bfloat16* __restrict__ A,
                                               const __hip_bfloat16* __restrict__ B,
                                               void* __restrict__ C0v, void* __restrict__ C1v,
                                               int M, int N, int K) {
  constexpr int WMG = BM / 64;
  constexpr int WNG = 4 / WMG;
  constexpr int NC = BN / (16 * WNG);
  int bx = blockIdx.x;
  int kbeg = 0, kend = K;
  if (SPLITX) {
    const int xhalf = gridDim.x >> 1;
    const int khalf = ((K >> 1) + 63) & ~63;
    if (bx >= xhalf) {
      bx -= xhalf;
      kbeg = khalf;
    } else {
      kend = khalf;
    }
  }
  const int row0 = blockIdx.y * BM, col0 = bx * BN;
  if (MIRROR && col0 + BN <= row0) return;  // fully below diagonal
  const bool do_mirror = MIRROR && (col0 > row0);
  __shared__ __attribute__((aligned(16))) __hip_bfloat16 As[2][BM * 64];
  __shared__ __attribute__((aligned(16))) __hip_bfloat16 Bs[2][BN * 64];
  const int tid = threadIdx.x;
  const int lane = tid & 63;
  const int wave = tid >> 6;
  const int wm = wave / WNG, wn = wave % WNG;
  const int r = lane & 15, q = lane >> 4;
  const int srow = tid >> 3;
  const int schunk = (tid & 7) ^ (srow & 7);

  f32x4 acc[4][NC];
#pragma unroll
  for (int a = 0; a < 4; ++a)
#pragma unroll
    for (int b = 0; b < NC; ++b) {
      f32x4 z = {0.f, 0.f, 0.f, 0.f};
      acc[a][b] = z;
    }

  const int niter = (kend - kbeg) >> 6;

#define STAGE(bufi, k0)                                                                       \
  {                                                                                           \
    _Pragma("unroll") for (int it = 0; it < BM / 32; ++it) {                                  \
      __builtin_amdgcn_global_load_lds(                                                       \
          (const __attribute__((address_space(1))) void*)(A + (size_t)(row0 + it * 32 + srow) * K + \
                                                          (k0) + schunk * 8),                 \
          (__attribute__((address_space(3))) void*)(&As[bufi][(it * 256 + tid) * 8]), 16, 0, 0); \
    }                                                                                         \
    _Pragma("unroll") for (int it = 0; it < BN / 32; ++it) {                                  \
      __builtin_amdgcn_global_load_lds(                                                       \
          (const __attribute__((address_space(1))) void*)(B + (size_t)(col0 + it * 32 + srow) * K + \
                                                          (k0) + schunk * 8),                 \
          (__attribute__((address_space(3))) void*)(&Bs[bufi][(it * 256 + tid) * 8]), 16, 0, 0); \
    }                                                                                         \
  }

  STAGE(0, kbeg)
  for (int k = 0; k < niter; ++k) {
    __syncthreads();
    if (k + 1 < niter) STAGE((k + 1) & 1, kbeg + ((k + 1) << 6))
    const __hip_bfloat16* as = As[k & 1];
    const __hip_bfloat16* bs = Bs[k & 1];
#pragma unroll
    for (int kk = 0; kk < 2; ++kk) {
      const int ch = ((kk * 4 + q) ^ (r & 7)) * 8;
      bf16x8 af[4], bfr[NC];
#pragma unroll
      for (int t = 0; t < 4; ++t)
        af[t] = *(const bf16x8*)(as + (wm * 64 + t * 16 + r) * 64 + ch);
#pragma unroll
      for (int c = 0; c < NC; ++c)
        bfr[c] = *(const bf16x8*)(bs + (wn * 16 * NC + c * 16 + r) * 64 + ch);
#pragma unroll
      for (int tm = 0; tm < 4; ++tm)
#pragma unroll
        for (int tn = 0; tn < NC; ++tn)
          acc[tm][tn] = __builtin_amdgcn_mfma_f32_16x16x32_bf16(af[tm], bfr[tn], acc[tm][tn], 0, 0, 0);
    }
  }
#undef STAGE
  float* dst = (float*)(SPLITX ? (kbeg > 0 ? C1v : C0v) : C0v);
  // C/D layout: col = lane&15, row = (lane>>4)*4 + reg   [guide §3, m89-verified]
#pragma unroll
  for (int tm = 0; tm < 4; ++tm) {
    int gr0 = row0 + wm * 64 + tm * 16 + q * 4;
#pragma unroll
    for (int tn = 0; tn < NC; ++tn) {
      int gc = col0 + wn * 16 * NC + tn * 16 + r;
#pragma unroll
      for (int p = 0; p < 4; ++p) {
        float vv = acc[tm][tn][p];
        if (RELU) vv = fmaxf(vv, 0.f);
        if (OUT_BF16) {
          ((__hip_bfloat16*)C0v)[(size_t)(gr0 + p) * N + gc] = __float2bfloat16(vv);
        } else {
          dst[(size_t)(gr0 + p) * N + gc] = vv;
          if (do_mirror) dst[(size_t)gc * N + (gr0 + p)] = vv;
        }
      }
    }
  }
}

// ------- 3) post: row->LDS, borderline repair in-LDS, softmax -> adj --------
__global__ __launch_bounds__(256) void post_kernel(const float* __restrict__ S,
                                                   __hip_bfloat16* __restrict__ adj,
                                                   const float* __restrict__ xpt,
                                                   const float* __restrict__ Wpt,
                                                   const float* __restrict__ norms) {
  __shared__ float rowv[L_DIM];  // 8KB: this row of S
  __shared__ float W4[KDIM];     // 19.2KB: w^4 table (built only if queue non-empty)
  __shared__ int lq[1024];
  __shared__ int lcount;
  __shared__ float red[4];
  const int b = blockIdx.x;
  const int tid = threadIdx.x;
  if (tid == 0) lcount = 0;
  __syncthreads();
  const float* s = S + (size_t)b * L_DIM;
  // load row into LDS + queue borderline entries (FULL row — no mirrors needed;
  // row j repairs (j,i) itself with the bitwise-identical computation)
  for (int j0 = tid * 4; j0 < L_DIM; j0 += 1024) {
    float4 v = *(const float4*)(s + j0);
    *(float4*)(&rowv[j0]) = v;
    float vv[4] = {v.x, v.y, v.z, v.w};
#pragma unroll
    for (int u = 0; u < 4; ++u) {
      if (fabsf(vv[u] - 0.1f) < WINDOW) {
        int p = atomicAdd(&lcount, 1);
        if (p < 1024) lq[p] = j0 + u;
      }
    }
  }
  __syncthreads();
  const int n = min(lcount, 1024);
  if (n > 0) {
    for (int e = tid; e < KDIM; e += 256) {
      float w = Wpt[e];
      float w2 = w * w;
      W4[e] = w2 * w2;
    }
    __syncthreads();
    const int lane = tid & 63;
    const int wave = tid >> 6;
    float xiv[5];
    float rni[H_DIM];  // hoisted 1/norm_i per head
    {
      const float* xi = xpt + b * EPT;
#pragma unroll
      for (int t = 0; t < 5; ++t) {
        int idx = lane + 64 * t;
        xiv[t] = idx < EPT ? xi[idx] : 0.f;
      }
#pragma unroll
      for (int h = 0; h < H_DIM; ++h) rni[h] = 1.f / norms[b * H_DIM + h];
    }
    for (int k = wave; k < n; k += 4) {
      int j = lq[k];
      const float* xj = xpt + j * EPT;
      float pre[5];
#pragma unroll
      for (int t = 0; t < 5; ++t) {
        int idx = lane + 64 * t;
        pre[t] = idx < EPT ? xiv[t] * xj[idx] : 0.f;
      }
      float accv = 0.f;
#pragma unroll
      for (int h = 0; h < H_DIM; ++h) {
        float ph = 0.f;
#pragma unroll
        for (int t = 0; t < 5; ++t) {
          int idx = lane + 64 * t;
          if (idx < EPT) ph += pre[t] * W4[h * EPT + idx];
        }
        accv += ph * (rni[h] / norms[j * H_DIM + h]);
      }
#pragma unroll
      for (int o = 32; o >= 1; o >>= 1) accv += __shfl_xor(accv, o, 64);
      if (lane == 0) rowv[j] = accv * (1.f / 16.f);
    }
    __syncthreads();
  }
  // softmax from LDS (same math as proven post)
  float m = -1e30f;
  for (int j = tid; j < L_DIM; j += 256) {
    float v = rowv[j];
    if (v >= 0.1f && v > m) m = v;
  }
#pragma unroll
  for (int o = 32; o >= 1; o >>= 1) m = fmaxf(m, __shfl_xor(m, o, 64));
  if ((tid & 63) == 0) red[tid >> 6] = m;
  __syncthreads();
  m = fmaxf(fmaxf(red[0], red[1]), fmaxf(red[2], red[3]));
  float sum = 0.f;
  for (int j = tid; j < L_DIM; j += 256) {
    float v = rowv[j];
    if (v >= 0.1f) sum += __expf(v - m);
  }
#pragma unroll
  for (int o = 32; o >= 1; o >>= 1) sum += __shfl_xor(sum, o, 64);
  __syncthreads();
  if ((tid & 63) == 0) red[tid >> 6] = sum;
  __syncthreads();
  sum = red[0] + red[1] + red[2] + red[3];
  float inv = 1.f / sum;
  for (int j = tid; j < L_DIM; j += 256) {
    float v = rowv[j];
    float a = (v >= 0.1f) ? __expf(v - m) * inv : 0.f;
    adj[(size_t)b * L_DIM + j] = __float2bfloat16(a);
  }
}

// ---------------- split-K combiners (R14-proven) ----------------
__global__ void combine_relu_bf16(const float* __restrict__ P0, const float* __restrict__ P1,
                                  __hip_bfloat16* __restrict__ X) {
  int i = blockIdx.x * 256 + threadIdx.x;
  float4 a = ((const float4*)P0)[i];
  float4 b = ((const float4*)P1)[i];
  __hip_bfloat16 o0 = __float2bfloat16(fmaxf(a.x + b.x, 0.f));
  __hip_bfloat16 o1 = __float2bfloat16(fmaxf(a.y + b.y, 0.f));
  __hip_bfloat16 o2 = __float2bfloat16(fmaxf(a.z + b.z, 0.f));
  __hip_bfloat16 o3 = __float2bfloat16(fmaxf(a.w + b.w, 0.f));
  X[4 * i + 0] = o0;
  X[4 * i + 1] = o1;
  X[4 * i + 2] = o2;
  X[4 * i + 3] = o3;
}

__global__ void combine_relu_f32(const float* __restrict__ P0, const float* __restrict__ P1,
                                 float* __restrict__ X) {
  int i = blockIdx.x * 256 + threadIdx.x;
  float4 a = ((const float4*)P0)[i];
  float4 b = ((const float4*)P1)[i];
  float4 v;
  v.x = fmaxf(a.x + b.x, 0.f);
  v.y = fmaxf(a.y + b.y, 0.f);
  v.z = fmaxf(a.z + b.z, 0.f);
  v.w = fmaxf(a.w + b.w, 0.f);
  ((float4*)X)[i] = v;
}

extern "C" void kernel_launch(void* const* d_in, const int* in_sizes, int n_in, void* d_out,
                              int out_size, void* d_ws, size_t ws_size, hipStream_t stream) {
  const float* label = (const float*)d_in[0];  // [2048,512]
  const float* xpt = (const float*)d_in[1];    // [2048,300]
  const float* Wpt = (const float*)d_in[2];    // [16,300]
  const float* W0 = (const float*)d_in[3];     // [512,512]
  const float* W1 = (const float*)d_in[4];     // [512,512]
  float* out = (float*)d_out;                  // [2048,512]

  // ---- layout (peak 47.1MB; ws >= 53.4MB proven) ----
  char* ws = (char*)d_ws;
  signed char* Y = (signed char*)ws;                    // [0, 9,830,400) live thru gram
  float* S = (float*)(ws + 19660800);                   // [19,660,800, 36,438,016)
  float* norms = (float*)(ws + 36438016);               // 128KB -> ends 36,569,088
  float* P0 = (float*)(ws + 36569088);                  // 4MB partial
  float* P1 = (float*)(ws + 40763392);                  // 4MB -> ends 44,957,696
  float* inv_s = (float*)(ws + 44957696);               // 8KB -> ends 44,965,888
  __hip_bfloat16* Lbf = (__hip_bfloat16*)(ws + 44965888);  // 2MB -> ends 47,063,040
  __hip_bfloat16* adj = (__hip_bfloat16*)ws;            // [0, 8,388,608) after post (Y dead)
  // GCN temporaries above Y's region (disjoint from Y [0,9.83M)):
  __hip_bfloat16* W0t = (__hip_bfloat16*)(ws + 10485760);   // 0.5MB
  __hip_bfloat16* W1t = (__hip_bfloat16*)(ws + 11010048);   // 0.5MB
  __hip_bfloat16* T0t = (__hip_bfloat16*)(ws + 11534336);   // 2MB [512x2048]
  __hip_bfloat16* X1 = (__hip_bfloat16*)(ws + 13631488);    // 2MB [2048x512]
  __hip_bfloat16* T1t = (__hip_bfloat16*)(ws + 15728640);   // 2MB -> ends 17,825,792

  // 1) Y-quant rows + label cast + W0/W1 transposes (one launch)
  prep_kernel<<<6656, 256, 0, stream>>>(xpt, Wpt, label, W0, W1, Y, norms, inv_s, Lbf, W0t, W1t);
  // 2) gram (triangle+mirror, XCD-swizzled, depth-3 counted-vmcnt) + T0t rider
  gram_i8<<<1024, 256, 0, stream>>>(Y, S, inv_s, W0t, Lbf, T0t);
  // 3) in-LDS borderline repair (1.5e-3 window) + softmax -> adj
  post_kernel<<<2048, 256, 0, stream>>>(S, adj, xpt, Wpt, norms);
  // 4) X1 = relu(adj @ T0t^T): split-K=2 -> P0/P1, combine
  gemm_bt<64, 64, false, false, false, true><<<dim3(16, 32), 256, 0, stream>>>(adj, T0t, P0, P1, 2048, 512, 2048);
  combine_relu_bf16<<<1024, 256, 0, stream>>>(P0, P1, X1);
  // 5) T1t = bf16(W1t @ X1^T)   [512 x 2048]
  gemm_bt<64, 64, false, true, false, false><<<dim3(32, 8), 256, 0, stream>>>(W1t, X1, T1t, nullptr, 512, 2048, 512);
  // 6) out = relu(adj @ T1t^T): split-K=2 -> P0/P1, combine into d_out
  gemm_bt<64, 64, false, false, false, true><<<dim3(16, 32), 256, 0, stream>>>(adj, T1t, P0, P1, 2048, 512, 2048);
  combine_relu_f32<<<1024, 256, 0, stream>>>(P0, P1, out);
}

// Round 8
// 180.862 us; speedup vs baseline: 1.2487x; 1.1325x over previous
//
#include <hip/hip_runtime.h>
#include <hip/hip_bf16.h>

// L=2048, E=512, E_PT=300, H=16. All inputs f32. Output f32 [2048,512].
//
// R25 = R24 (proven 204.8us) with two fusions driven by the dispatch ledger
// (8 dispatches x ~8.4us inter-dispatch cost measured across R23/R24):
//  - gemm_adj_fused: 512-thread, 2 wave-groups each running the PROVEN
//    64x64/BK=64 body on one K-half (16 iters, own 32KB LDS half);
//    epilogue: group1 acc -> LDS (16KB, its own As region, barrier-fenced),
//    group0 adds + ReLU + stores. Bitwise == P0+P1 combiner. Kills both
//    combine dispatches AND the 33MB P0/P1 round-trip.
//  - post repair W4: LDS table -> registers w4i[16][5] = w^4 * (1/n_i),
//    loaded once per block; norms buffer now stores reciprocals (prep),
//    so repair is pure FMA + broadcast loads (~2.5x less issue than the
//    ds_read_b32-bound R24 loop). LDS 31.5 -> 12.3KB.
//  - prep, gram_i8(+T0t rider), T1t GEMM = R24 verbatim.
// Dispatches (6): prep -> gram(+rider) -> post -> adjG1(fused) -> T1t
//                 -> adjG2(fused).

typedef __attribute__((ext_vector_type(8))) short bf16x8;
typedef __attribute__((ext_vector_type(4))) float f32x4;
typedef __attribute__((ext_vector_type(4))) int i32x4;

#define L_DIM 2048
#define EPT 300
#define H_DIM 16
#define KDIM 4800
#define WINDOW 1.5e-3f  // two-sided borderline window (~8 sigma of i8 error)

// ------- 1) prep: Y(i8 per-row) + RECIPROCAL norms + inv_s | cast | W^T -----
// grid 6656: [0,2048) y-rows; [2048,6144) label cast; [6144,6656) transpose.
__global__ __launch_bounds__(256) void prep_kernel(const float* __restrict__ xpt,
                                                   const float* __restrict__ Wpt,
                                                   const float* __restrict__ label,
                                                   const float* __restrict__ W0,
                                                   const float* __restrict__ W1,
                                                   signed char* __restrict__ Y,
                                                   float* __restrict__ rnorms,
                                                   float* __restrict__ inv_s,
                                                   __hip_bfloat16* __restrict__ Lbf,
                                                   __hip_bfloat16* __restrict__ W0t,
                                                   __hip_bfloat16* __restrict__ W1t) {
  __shared__ float redmax[4];
  __shared__ float tile[32][33];
  const int b = blockIdx.x;
  const int tid = threadIdx.x;
  if (b < 2048) {
    const int i = b;  // row
    const int lane = tid & 63;
    const int w = tid >> 6;  // wave 0..3 -> heads 4w..4w+3
    const float* x = xpt + i * EPT;
    float y[4][5];
    float wmax = 0.f;
#pragma unroll
    for (int hh = 0; hh < 4; ++hh) {
      const int h = w * 4 + hh;
      const float* wp = Wpt + h * EPT;
      float ss = 0.f;
#pragma unroll
      for (int t = 0; t < 5; ++t) {
        int e = lane + 64 * t;
        float val = 0.f;
        if (e < EPT) {
          float we = wp[e];
          val = x[e] * we * we;
        }
        y[hh][t] = val;
        ss += val * val;
      }
#pragma unroll
      for (int o = 32; o >= 1; o >>= 1) ss += __shfl_xor(ss, o, 64);
      float n = fmaxf(sqrtf(ss), 1e-12f);
      if (lane == 0) rnorms[i * H_DIM + h] = 1.0f / n;  // reciprocal (post uses mult)
      float scale = 0.25f / n;  // per-head y = v/(norm*sqrt(H)); |y| <= 0.25
#pragma unroll
      for (int t = 0; t < 5; ++t) {
        y[hh][t] *= scale;
        wmax = fmaxf(wmax, fabsf(y[hh][t]));
      }
    }
#pragma unroll
    for (int o = 32; o >= 1; o >>= 1) wmax = fmaxf(wmax, __shfl_xor(wmax, o, 64));
    if (lane == 0) redmax[w] = wmax;
    __syncthreads();
    float rowmax = fmaxf(fmaxf(redmax[0], redmax[1]), fmaxf(redmax[2], redmax[3]));
    rowmax = fmaxf(rowmax, 1e-12f);
    const float qs = 127.0f / rowmax;
    if (tid == 0) inv_s[i] = rowmax * (1.0f / 127.0f);
#pragma unroll
    for (int hh = 0; hh < 4; ++hh) {
      const int h = w * 4 + hh;
#pragma unroll
      for (int t = 0; t < 5; ++t) {
        int e = lane + 64 * t;
        if (e < EPT) {
          int qv = __float2int_rn(y[hh][t] * qs);
          qv = max(-127, min(127, qv));
          Y[(size_t)i * KDIM + h * EPT + e] = (signed char)qv;
        }
      }
    }
    return;
  }
  if (b < 6144) {
    int i = (b - 2048) * 256 + tid;
    Lbf[i] = __float2bfloat16(label[i]);
    return;
  }
  int local = b - 6144;
  const bool first = local < 256;
  const float* src = first ? W0 : W1;
  __hip_bfloat16* dst = first ? W0t : W1t;
  int rem = local & 255;
  int c0 = (rem & 15) * 32, r0 = (rem >> 4) * 32;
  int tx = tid & 31, ty = tid >> 5;
  for (int i2 = ty; i2 < 32; i2 += 8) tile[i2][tx] = src[(size_t)(r0 + i2) * 512 + c0 + tx];
  __syncthreads();
  for (int i2 = ty; i2 < 32; i2 += 8)
    dst[(size_t)(c0 + i2) * 512 + r0 + tx] = __float2bfloat16(tile[tx][i2]);
}

// ---------------- 2) int8 gram (R22-proven) + T0t RIDER on dead blocks ------
__global__ __launch_bounds__(256) void gram_i8(const signed char* __restrict__ Y,
                                               float* __restrict__ S,
                                               const float* __restrict__ inv_s,
                                               const __hip_bfloat16* __restrict__ W0t,
                                               const __hip_bfloat16* __restrict__ Lbf,
                                               __hip_bfloat16* __restrict__ T0t) {
  __shared__ __attribute__((aligned(16))) char smem[32768];
  // XCD-locality remap: XCD k (id%8) owns col-tiles {k, k+8, k+16, k+24}
  const int id = blockIdx.x;
  const int bx = (id & 7) | (((id >> 3) & 3) << 3);
  const int by = id >> 5;
  const int row0 = by * 64, col0 = bx * 64;
  const int tid = threadIdx.x;
  const int lane = tid & 63;
  const int wn = tid >> 6;
  const int r = lane & 15, q = lane >> 4;

  if (col0 + 64 <= row0) {
    // ---- RIDER: T0t tile GEMM (dead gram slot), R23/R24-proven ----
    const int d = (by * (by - 1)) / 2 + bx;  // 0..495 (bx < by)
    if (d >= 256) return;
    const int row0r = (d >> 5) * 64;  // [0,512)
    const int col0r = (d & 31) * 64;  // [0,2048)
    __hip_bfloat16* Asb = (__hip_bfloat16*)smem;             // [2][4096] bf16
    __hip_bfloat16* Bsb = (__hip_bfloat16*)(smem + 16384);   // [2][4096] bf16
    const int srow8 = tid >> 3;
    const int schunk8 = (tid & 7) ^ (srow8 & 7);
    f32x4 racc[4];
#pragma unroll
    for (int t = 0; t < 4; ++t) {
      f32x4 z = {0.f, 0.f, 0.f, 0.f};
      racc[t] = z;
    }
#define RSTAGE(bufi, k0)                                                                      \
  {                                                                                           \
    _Pragma("unroll") for (int it = 0; it < 2; ++it) {                                        \
      __builtin_amdgcn_global_load_lds(                                                       \
          (const __attribute__((address_space(1))) void*)(W0t + (size_t)(row0r + it * 32 + srow8) * 512 + \
                                                          (k0) + schunk8 * 8),                \
          (__attribute__((address_space(3))) void*)(Asb + (bufi)*4096 + (it * 256 + tid) * 8), 16, 0, 0); \
    }                                                                                         \
    _Pragma("unroll") for (int it = 0; it < 2; ++it) {                                        \
      __builtin_amdgcn_global_load_lds(                                                       \
          (const __attribute__((address_space(1))) void*)(Lbf + (size_t)(col0r + it * 32 + srow8) * 512 + \
                                                          (k0) + schunk8 * 8),                \
          (__attribute__((address_space(3))) void*)(Bsb + (bufi)*4096 + (it * 256 + tid) * 8), 16, 0, 0); \
    }                                                                                         \
  }
    RSTAGE(0, 0)
    for (int k = 0; k < 8; ++k) {
      __syncthreads();
      if (k + 1 < 8) RSTAGE((k + 1) & 1, (k + 1) * 64)
      const __hip_bfloat16* as = Asb + (k & 1) * 4096;
      const __hip_bfloat16* bs = Bsb + (k & 1) * 4096;
#pragma unroll
      for (int kk = 0; kk < 2; ++kk) {
        const int ch = ((kk * 4 + q) ^ (r & 7)) * 8;
        bf16x8 af[4];
#pragma unroll
        for (int t = 0; t < 4; ++t) af[t] = *(const bf16x8*)(as + (t * 16 + r) * 64 + ch);
        bf16x8 bfr = *(const bf16x8*)(bs + (wn * 16 + r) * 64 + ch);
#pragma unroll
        for (int t = 0; t < 4; ++t)
          racc[t] = __builtin_amdgcn_mfma_f32_16x16x32_bf16(af[t], bfr, racc[t], 0, 0, 0);
      }
    }
#undef RSTAGE
    const int gcr = col0r + wn * 16 + r;
#pragma unroll
    for (int t = 0; t < 4; ++t) {
      int gr0 = row0r + t * 16 + q * 4;
#pragma unroll
      for (int p = 0; p < 4; ++p)
        T0t[(size_t)(gr0 + p) * 2048 + gcr] = __float2bfloat16(racc[t][p]);
    }
    return;
  }

  // ---- gram main path (R22 verbatim) ----
  const bool do_mirror = (col0 > row0);
  signed char* As = (signed char*)smem;           // [4][4096] i8
  signed char* Bs = (signed char*)(smem + 16384); // [4][4096] i8
  const int srow = tid >> 2;                     // staging row 0..63
  const int sc = (tid & 3) ^ ((srow >> 2) & 3);  // global 16B chunk for this slot

  i32x4 acc[4];
#pragma unroll
  for (int t = 0; t < 4; ++t) {
    i32x4 z = {0, 0, 0, 0};
    acc[t] = z;
  }
  const int niter = KDIM / 64;  // 75

#define STAGEI(bufi, k0)                                                                       \
  {                                                                                            \
    __builtin_amdgcn_global_load_lds(                                                          \
        (const __attribute__((address_space(1))) void*)(Y + (size_t)(row0 + srow) * KDIM +     \
                                                        (k0) + sc * 16),                       \
        (__attribute__((address_space(3))) void*)(As + (bufi)*4096 + tid * 16), 16, 0, 0);     \
    __builtin_amdgcn_global_load_lds(                                                          \
        (const __attribute__((address_space(1))) void*)(Y + (size_t)(col0 + srow) * KDIM +     \
                                                        (k0) + sc * 16),                       \
        (__attribute__((address_space(3))) void*)(Bs + (bufi)*4096 + tid * 16), 16, 0, 0);     \
  }

  auto compute = [&](int bufi) {
    const signed char* as = As + bufi * 4096;
    const signed char* bs = Bs + bufi * 4096;
    const int ch = (q ^ ((r >> 2) & 3)) * 16;  // swizzled 16B chunk
    i32x4 bfrag = *(const i32x4*)(bs + (wn * 16 + r) * 64 + ch);
#pragma unroll
    for (int t = 0; t < 4; ++t) {
      i32x4 afrag = *(const i32x4*)(as + (t * 16 + r) * 64 + ch);
      acc[t] = __builtin_amdgcn_mfma_i32_16x16x64_i8(afrag, bfrag, acc[t], 0, 0, 0);
    }
  };

  STAGEI(0, 0)
  STAGEI(1, 64)
  STAGEI(2, 128)
  for (int k = 0; k < niter - 3; ++k) {
    asm volatile("s_waitcnt vmcnt(4)" ::: "memory");
    __builtin_amdgcn_s_barrier();
    __builtin_amdgcn_sched_barrier(0);
    STAGEI((k + 3) & 3, (k + 3) * 64)
    compute(k & 3);
  }
  asm volatile("s_waitcnt vmcnt(4)" ::: "memory");
  __builtin_amdgcn_s_barrier();
  __builtin_amdgcn_sched_barrier(0);
  compute((niter - 3) & 3);
  asm volatile("s_waitcnt vmcnt(2)" ::: "memory");
  __builtin_amdgcn_s_barrier();
  __builtin_amdgcn_sched_barrier(0);
  compute((niter - 2) & 3);
  asm volatile("s_waitcnt vmcnt(0)" ::: "memory");
  __builtin_amdgcn_s_barrier();
  __builtin_amdgcn_sched_barrier(0);
  compute((niter - 1) & 3);
#undef STAGEI
  // C/D layout: col = lane&15, row = (lane>>4)*4 + reg (shape-determined)
  const int gc = col0 + wn * 16 + r;
  const float sj = inv_s[gc];
#pragma unroll
  for (int t = 0; t < 4; ++t) {
    int gr0 = row0 + t * 16 + q * 4;
#pragma unroll
    for (int p = 0; p < 4; ++p) {
      float vv = (float)acc[t][p] * (inv_s[gr0 + p] * sj);
      S[(size_t)(gr0 + p) * L_DIM + gc] = vv;
      if (do_mirror) S[(size_t)gc * L_DIM + (gr0 + p)] = vv;
    }
  }
}

// ---------------- 2b) bf16 bt-GEMM (R17-proven, BK=64; used for T1t) --------
template <int BM, int BN, bool RELU, bool OUT_BF16>
__global__ __launch_bounds__(256) void gemm_bt(const __hip_bfloat16* __restrict__ A,
                                               const __hip_bfloat16* __restrict__ B,
                                               void* __restrict__ C0v,
                                               int M, int N, int K) {
  constexpr int WMG = BM / 64;
  constexpr int WNG = 4 / WMG;
  constexpr int NC = BN / (16 * WNG);
  const int row0 = blockIdx.y * BM, col0 = blockIdx.x * BN;
  __shared__ __attribute__((aligned(16))) __hip_bfloat16 As[2][BM * 64];
  __shared__ __attribute__((aligned(16))) __hip_bfloat16 Bs[2][BN * 64];
  const int tid = threadIdx.x;
  const int lane = tid & 63;
  const int wave = tid >> 6;
  const int wm = wave / WNG, wn = wave % WNG;
  const int r = lane & 15, q = lane >> 4;
  const int srow = tid >> 3;
  const int schunk = (tid & 7) ^ (srow & 7);

  f32x4 acc[4][NC];
#pragma unroll
  for (int a = 0; a < 4; ++a)
#pragma unroll
    for (int b = 0; b < NC; ++b) {
      f32x4 z = {0.f, 0.f, 0.f, 0.f};
      acc[a][b] = z;
    }

  const int niter = K >> 6;

#define STAGE(bufi, k0)                                                                       \
  {                                                                                           \
    _Pragma("unroll") for (int it = 0; it < BM / 32; ++it) {                                  \
      __builtin_amdgcn_global_load_lds(                                                       \
          (const __attribute__((address_space(1))) void*)(A + (size_t)(row0 + it * 32 + srow) * K + \
                                                          (k0) + schunk * 8),                 \
          (__attribute__((address_space(3))) void*)(&As[bufi][(it * 256 + tid) * 8]), 16, 0, 0); \
    }                                                                                         \
    _Pragma("unroll") for (int it = 0; it < BN / 32; ++it) {                                  \
      __builtin_amdgcn_global_load_lds(                                                       \
          (const __attribute__((address_space(1))) void*)(B + (size_t)(col0 + it * 32 + srow) * K + \
                                                          (k0) + schunk * 8),                 \
          (__attribute__((address_space(3))) void*)(&Bs[bufi][(it * 256 + tid) * 8]), 16, 0, 0); \
    }                                                                                         \
  }

  STAGE(0, 0)
  for (int k = 0; k < niter; ++k) {
    __syncthreads();
    if (k + 1 < niter) STAGE((k + 1) & 1, (k + 1) << 6)
    const __hip_bfloat16* as = As[k & 1];
    const __hip_bfloat16* bs = Bs[k & 1];
#pragma unroll
    for (int kk = 0; kk < 2; ++kk) {
      const int ch = ((kk * 4 + q) ^ (r & 7)) * 8;
      bf16x8 af[4], bfr[NC];
#pragma unroll
      for (int t = 0; t < 4; ++t)
        af[t] = *(const bf16x8*)(as + (wm * 64 + t * 16 + r) * 64 + ch);
#pragma unroll
      for (int c = 0; c < NC; ++c)
        bfr[c] = *(const bf16x8*)(bs + (wn * 16 * NC + c * 16 + r) * 64 + ch);
#pragma unroll
      for (int tm = 0; tm < 4; ++tm)
#pragma unroll
        for (int tn = 0; tn < NC; ++tn)
          acc[tm][tn] = __builtin_amdgcn_mfma_f32_16x16x32_bf16(af[tm], bfr[tn], acc[tm][tn], 0, 0, 0);
    }
  }
#undef STAGE
  // C/D layout: col = lane&15, row = (lane>>4)*4 + reg   [guide §3, m89-verified]
#pragma unroll
  for (int tm = 0; tm < 4; ++tm) {
    int gr0 = row0 + wm * 64 + tm * 16 + q * 4;
#pragma unroll
    for (int tn = 0; tn < NC; ++tn) {
      int gc = col0 + wn * 16 * NC + tn * 16 + r;
#pragma unroll
      for (int p = 0; p < 4; ++p) {
        float vv = acc[tm][tn][p];
        if (RELU) vv = fmaxf(vv, 0.f);
        if (OUT_BF16) {
          ((__hip_bfloat16*)C0v)[(size_t)(gr0 + p) * N + gc] = __float2bfloat16(vv);
        } else {
          ((float*)C0v)[(size_t)(gr0 + p) * N + gc] = vv;
        }
      }
    }
  }
}

// ------ 2c) fused split-K adj GEMM: 512 thr, 2 groups, in-block combine -----
// C = relu(A @ B^T): A [2048 x 2048] bf16, B [512 x 2048] bf16, C [2048 x 512].
// Group g (waves 4g..4g+3) computes K-half [g*1024, g*1024+1024) with the
// proven 64x64/BK=64 body in its own 32KB LDS half. Epilogue: group1 acc ->
// LDS (its own As region), group0 adds + ReLU + stores. == P0+P1 combiner.
template <bool OUT_BF16>
__global__ __launch_bounds__(512) void gemm_adj_fused(const __hip_bfloat16* __restrict__ A,
                                                      const __hip_bfloat16* __restrict__ B,
                                                      void* __restrict__ C0v) {
  constexpr int K = 2048, N = 512;
  __shared__ __attribute__((aligned(16))) __hip_bfloat16 sm[4][2][4096];  // 64KB
  const int tid = threadIdx.x;
  const int grp = tid >> 8;        // 0,1 -> K-half
  const int gtid = tid & 255;
  const int lane = tid & 63;
  const int wn = (tid >> 6) & 3;   // same for tid and tid+256
  const int r = lane & 15, q = lane >> 4;
  const int srow = gtid >> 3;
  const int schunk = (gtid & 7) ^ (srow & 7);
  const int row0 = blockIdx.y * 64, col0 = blockIdx.x * 64;
  const int kbeg = grp * 1024;
  __hip_bfloat16* As = &sm[grp * 2 + 0][0][0];
  __hip_bfloat16* Bs = &sm[grp * 2 + 1][0][0];

  f32x4 acc[4];
#pragma unroll
  for (int t = 0; t < 4; ++t) {
    f32x4 z = {0.f, 0.f, 0.f, 0.f};
    acc[t] = z;
  }

#define FSTAGE(bufi, k0)                                                                      \
  {                                                                                           \
    _Pragma("unroll") for (int it = 0; it < 2; ++it) {                                        \
      __builtin_amdgcn_global_load_lds(                                                       \
          (const __attribute__((address_space(1))) void*)(A + (size_t)(row0 + it * 32 + srow) * K + \
                                                          (k0) + schunk * 8),                 \
          (__attribute__((address_space(3))) void*)(As + (bufi)*4096 + (it * 256 + gtid) * 8), 16, 0, 0); \
    }                                                                                         \
    _Pragma("unroll") for (int it = 0; it < 2; ++it) {                                        \
      __builtin_amdgcn_global_load_lds(                                                       \
          (const __attribute__((address_space(1))) void*)(B + (size_t)(col0 + it * 32 + srow) * K + \
                                                          (k0) + schunk * 8),                 \
          (__attribute__((address_space(3))) void*)(Bs + (bufi)*4096 + (it * 256 + gtid) * 8), 16, 0, 0); \
    }                                                                                         \
  }

  FSTAGE(0, kbeg)
  for (int k = 0; k < 16; ++k) {
    __syncthreads();
    if (k + 1 < 16) FSTAGE((k + 1) & 1, kbeg + ((k + 1) << 6))
    const __hip_bfloat16* as = As + (k & 1) * 4096;
    const __hip_bfloat16* bs = Bs + (k & 1) * 4096;
#pragma unroll
    for (int kk = 0; kk < 2; ++kk) {
      const int ch = ((kk * 4 + q) ^ (r & 7)) * 8;
      bf16x8 af[4];
#pragma unroll
      for (int t = 0; t < 4; ++t) af[t] = *(const bf16x8*)(as + (t * 16 + r) * 64 + ch);
      bf16x8 bfr = *(const bf16x8*)(bs + (wn * 16 + r) * 64 + ch);
#pragma unroll
      for (int t = 0; t < 4; ++t)
        acc[t] = __builtin_amdgcn_mfma_f32_16x16x32_bf16(af[t], bfr, acc[t], 0, 0, 0);
    }
  }
#undef FSTAGE
  // in-block split-K combine (exact f32 add, == combiner kernels)
  __syncthreads();  // all compute done before group1 overwrites its As region
  float* F = (float*)&sm[2][0][0];  // 16KB, group1's As region
  if (grp == 1) {
#pragma unroll
    for (int tm = 0; tm < 4; ++tm)
#pragma unroll
      for (int p = 0; p < 4; ++p) F[gtid * 16 + tm * 4 + p] = acc[tm][p];
  }
  __syncthreads();
  if (grp == 0) {
#pragma unroll
    for (int tm = 0; tm < 4; ++tm) {
      int gr0 = row0 + tm * 16 + q * 4;
      int gc = col0 + wn * 16 + r;
#pragma unroll
      for (int p = 0; p < 4; ++p) {
        float vv = fmaxf(acc[tm][p] + F[gtid * 16 + tm * 4 + p], 0.f);
        if (OUT_BF16) {
          ((__hip_bfloat16*)C0v)[(size_t)(gr0 + p) * N + gc] = __float2bfloat16(vv);
        } else {
          ((float*)C0v)[(size_t)(gr0 + p) * N + gc] = vv;
        }
      }
    }
  }
}

// ------- 3) post: row->LDS, repair with W4-in-REGISTERS, softmax -> adj -----
__global__ __launch_bounds__(256) void post_kernel(const float* __restrict__ S,
                                                   __hip_bfloat16* __restrict__ adj,
                                                   const float* __restrict__ xpt,
                                                   const float* __restrict__ Wpt,
                                                   const float* __restrict__ rnorms) {
  __shared__ float rowv[L_DIM];  // 8KB: this row of S
  __shared__ int lq[1024];
  __shared__ int lcount;
  __shared__ float red[4];
  const int b = blockIdx.x;
  const int tid = threadIdx.x;
  if (tid == 0) lcount = 0;
  __syncthreads();
  const float* s = S + (size_t)b * L_DIM;
  // load row into LDS + queue borderline entries (FULL row — no mirrors needed;
  // row j repairs (j,i) itself with the bitwise-identical computation)
  for (int j0 = tid * 4; j0 < L_DIM; j0 += 1024) {
    float4 v = *(const float4*)(s + j0);
    *(float4*)(&rowv[j0]) = v;
    float vv[4] = {v.x, v.y, v.z, v.w};
#pragma unroll
    for (int u = 0; u < 4; ++u) {
      if (fabsf(vv[u] - 0.1f) < WINDOW) {
        int p = atomicAdd(&lcount, 1);
        if (p < 1024) lq[p] = j0 + u;
      }
    }
  }
  __syncthreads();
  const int n = min(lcount, 1024);
  if (n > 0) {
    const int lane = tid & 63;
    const int wave = tid >> 6;
    float xiv[5];
    float w4i[H_DIM][5];  // registers: w^4 * (1/n_i) — fully unrolled indices
    {
      const float* xi = xpt + b * EPT;
#pragma unroll
      for (int t = 0; t < 5; ++t) {
        int idx = lane + 64 * t;
        xiv[t] = idx < EPT ? xi[idx] : 0.f;
      }
#pragma unroll
      for (int h = 0; h < H_DIM; ++h) {
        float rni = rnorms[b * H_DIM + h];
#pragma unroll
        for (int t = 0; t < 5; ++t) {
          int idx = lane + 64 * t;
          float w = idx < EPT ? Wpt[h * EPT + idx] : 0.f;
          float w2 = w * w;
          w4i[h][t] = w2 * w2 * rni;
        }
      }
    }
    for (int k = wave; k < n; k += 4) {
      int j = lq[k];
      const float* xj = xpt + j * EPT;
      float pre[5];
#pragma unroll
      for (int t = 0; t < 5; ++t) {
        int idx = lane + 64 * t;
        pre[t] = idx < EPT ? xiv[t] * xj[idx] : 0.f;
      }
      float accv = 0.f;
#pragma unroll
      for (int h = 0; h < H_DIM; ++h) {
        float ph = 0.f;
#pragma unroll
        for (int t = 0; t < 5; ++t) ph += pre[t] * w4i[h][t];
        accv += ph * rnorms[j * H_DIM + h];  // broadcast load (uniform addr)
      }
#pragma unroll
      for (int o = 32; o >= 1; o >>= 1) accv += __shfl_xor(accv, o, 64);
      if (lane == 0) rowv[j] = accv * (1.f / 16.f);
    }
    __syncthreads();
  }
  // softmax from LDS (same math as proven post)
  float m = -1e30f;
  for (int j = tid; j < L_DIM; j += 256) {
    float v = rowv[j];
    if (v >= 0.1f && v > m) m = v;
  }
#pragma unroll
  for (int o = 32; o >= 1; o >>= 1) m = fmaxf(m, __shfl_xor(m, o, 64));
  if ((tid & 63) == 0) red[tid >> 6] = m;
  __syncthreads();
  m = fmaxf(fmaxf(red[0], red[1]), fmaxf(red[2], red[3]));
  float sum = 0.f;
  for (int j = tid; j < L_DIM; j += 256) {
    float v = rowv[j];
    if (v >= 0.1f) sum += __expf(v - m);
  }
#pragma unroll
  for (int o = 32; o >= 1; o >>= 1) sum += __shfl_xor(sum, o, 64);
  __syncthreads();
  if ((tid & 63) == 0) red[tid >> 6] = sum;
  __syncthreads();
  sum = red[0] + red[1] + red[2] + red[3];
  float inv = 1.f / sum;
  for (int j = tid; j < L_DIM; j += 256) {
    float v = rowv[j];
    float a = (v >= 0.1f) ? __expf(v - m) * inv : 0.f;
    adj[(size_t)b * L_DIM + j] = __float2bfloat16(a);
  }
}

extern "C" void kernel_launch(void* const* d_in, const int* in_sizes, int n_in, void* d_out,
                              int out_size, void* d_ws, size_t ws_size, hipStream_t stream) {
  const float* label = (const float*)d_in[0];  // [2048,512]
  const float* xpt = (const float*)d_in[1];    // [2048,300]
  const float* Wpt = (const float*)d_in[2];    // [16,300]
  const float* W0 = (const float*)d_in[3];     // [512,512]
  const float* W1 = (const float*)d_in[4];     // [512,512]
  float* out = (float*)d_out;                  // [2048,512]

  // ---- layout (peak 47.1MB; ws >= 53.4MB proven) ----
  char* ws = (char*)d_ws;
  signed char* Y = (signed char*)ws;                    // [0, 9,830,400) live thru gram
  float* S = (float*)(ws + 19660800);                   // [19,660,800, 36,438,016)
  float* rnorms = (float*)(ws + 36438016);              // 128KB -> ends 36,569,088
  float* inv_s = (float*)(ws + 44957696);               // 8KB -> ends 44,965,888
  __hip_bfloat16* Lbf = (__hip_bfloat16*)(ws + 44965888);  // 2MB -> ends 47,063,040
  __hip_bfloat16* adj = (__hip_bfloat16*)ws;            // [0, 8,388,608) after post (Y dead)
  // GCN temporaries above Y's region (disjoint from Y [0,9.83M)):
  __hip_bfloat16* W0t = (__hip_bfloat16*)(ws + 10485760);   // 0.5MB
  __hip_bfloat16* W1t = (__hip_bfloat16*)(ws + 11010048);   // 0.5MB
  __hip_bfloat16* T0t = (__hip_bfloat16*)(ws + 11534336);   // 2MB [512x2048]
  __hip_bfloat16* X1 = (__hip_bfloat16*)(ws + 13631488);    // 2MB [2048x512]
  __hip_bfloat16* T1t = (__hip_bfloat16*)(ws + 15728640);   // 2MB -> ends 17,825,792

  // 1) Y-quant rows (reciprocal norms) + label cast + W0/W1 transposes
  prep_kernel<<<6656, 256, 0, stream>>>(xpt, Wpt, label, W0, W1, Y, rnorms, inv_s, Lbf, W0t, W1t);
  // 2) gram (triangle+mirror, XCD-swizzled, depth-3 counted-vmcnt) + T0t rider
  gram_i8<<<1024, 256, 0, stream>>>(Y, S, inv_s, W0t, Lbf, T0t);
  // 3) in-LDS borderline repair (W4 in registers) + softmax -> adj
  post_kernel<<<2048, 256, 0, stream>>>(S, adj, xpt, Wpt, rnorms);
  // 4) X1 = relu_bf16(adj @ T0t^T): fused in-block split-K=2
  gemm_adj_fused<true><<<dim3(8, 32), 512, 0, stream>>>(adj, T0t, X1);
  // 5) T1t = bf16(W1t @ X1^T)   [512 x 2048]
  gemm_bt<64, 64, false, true><<<dim3(32, 8), 256, 0, stream>>>(W1t, X1, T1t, 512, 2048, 512);
  // 6) out = relu_f32(adj @ T1t^T): fused in-block split-K=2
  gemm_adj_fused<false><<<dim3(8, 32), 512, 0, stream>>>(adj, T1t, out);
}

// Round 9
// 173.852 us; speedup vs baseline: 1.2991x; 1.0403x over previous
//
#include <hip/hip_runtime.h>
#include <hip/hip_bf16.h>

// L=2048, E=512, E_PT=300, H=16. All inputs f32. Output f32 [2048,512].
//
// R26 = R25 (proven 180.9us) + BK=128 i8 gram (iteration-count attack):
//  - Ledger: gram 51us = 28% of wall; per-iteration cost ~670cy is fixed
//    machinery (2 barriers + ds/MFMA chain) — R18 concurrency null, R22
//    depth-3 null, R21 bytes -18%. Halve the ITERATION COUNT: BK 64->128,
//    75 -> 38 iters (37 full + peeled 64-tail; i32 accum exact, order-free).
//  - Why R19's BK=128 failure doesn't apply: i8 tile is 8KB (not 16KB) so
//    LDS stays 32KB (occupancy unchanged), and the [64][128B] i8 tile is
//    byte-identical addressing to the PROVEN bf16 [64][128B] tile (0
//    conflicts measured R14-R17): stage src_chunk = c^(row&7), read
//    ch = ((kk*4+q)^(r&7))*16. Kills the 3.17M conflicts of the old
//    [64][64B] layout too.
//  - Tail (k=4736..4800) uses the R21/R22-proven [64][64B] stage+compute.
//  - Everything else = R25 verbatim (prep, rider, post W4-in-regs,
//    fused adj GEMMs, T1t).
// Dispatches (6): prep -> gram(+rider) -> post -> adjG1(fused) -> T1t
//                 -> adjG2(fused).

typedef __attribute__((ext_vector_type(8))) short bf16x8;
typedef __attribute__((ext_vector_type(4))) float f32x4;
typedef __attribute__((ext_vector_type(4))) int i32x4;

#define L_DIM 2048
#define EPT 300
#define H_DIM 16
#define KDIM 4800
#define WINDOW 1.5e-3f  // two-sided borderline window (~8 sigma of i8 error)

// ------- 1) prep: Y(i8 per-row) + RECIPROCAL norms + inv_s | cast | W^T -----
// grid 6656: [0,2048) y-rows; [2048,6144) label cast; [6144,6656) transpose.
__global__ __launch_bounds__(256) void prep_kernel(const float* __restrict__ xpt,
                                                   const float* __restrict__ Wpt,
                                                   const float* __restrict__ label,
                                                   const float* __restrict__ W0,
                                                   const float* __restrict__ W1,
                                                   signed char* __restrict__ Y,
                                                   float* __restrict__ rnorms,
                                                   float* __restrict__ inv_s,
                                                   __hip_bfloat16* __restrict__ Lbf,
                                                   __hip_bfloat16* __restrict__ W0t,
                                                   __hip_bfloat16* __restrict__ W1t) {
  __shared__ float redmax[4];
  __shared__ float tile[32][33];
  const int b = blockIdx.x;
  const int tid = threadIdx.x;
  if (b < 2048) {
    const int i = b;  // row
    const int lane = tid & 63;
    const int w = tid >> 6;  // wave 0..3 -> heads 4w..4w+3
    const float* x = xpt + i * EPT;
    float y[4][5];
    float wmax = 0.f;
#pragma unroll
    for (int hh = 0; hh < 4; ++hh) {
      const int h = w * 4 + hh;
      const float* wp = Wpt + h * EPT;
      float ss = 0.f;
#pragma unroll
      for (int t = 0; t < 5; ++t) {
        int e = lane + 64 * t;
        float val = 0.f;
        if (e < EPT) {
          float we = wp[e];
          val = x[e] * we * we;
        }
        y[hh][t] = val;
        ss += val * val;
      }
#pragma unroll
      for (int o = 32; o >= 1; o >>= 1) ss += __shfl_xor(ss, o, 64);
      float n = fmaxf(sqrtf(ss), 1e-12f);
      if (lane == 0) rnorms[i * H_DIM + h] = 1.0f / n;  // reciprocal (post uses mult)
      float scale = 0.25f / n;  // per-head y = v/(norm*sqrt(H)); |y| <= 0.25
#pragma unroll
      for (int t = 0; t < 5; ++t) {
        y[hh][t] *= scale;
        wmax = fmaxf(wmax, fabsf(y[hh][t]));
      }
    }
#pragma unroll
    for (int o = 32; o >= 1; o >>= 1) wmax = fmaxf(wmax, __shfl_xor(wmax, o, 64));
    if (lane == 0) redmax[w] = wmax;
    __syncthreads();
    float rowmax = fmaxf(fmaxf(redmax[0], redmax[1]), fmaxf(redmax[2], redmax[3]));
    rowmax = fmaxf(rowmax, 1e-12f);
    const float qs = 127.0f / rowmax;
    if (tid == 0) inv_s[i] = rowmax * (1.0f / 127.0f);
#pragma unroll
    for (int hh = 0; hh < 4; ++hh) {
      const int h = w * 4 + hh;
#pragma unroll
      for (int t = 0; t < 5; ++t) {
        int e = lane + 64 * t;
        if (e < EPT) {
          int qv = __float2int_rn(y[hh][t] * qs);
          qv = max(-127, min(127, qv));
          Y[(size_t)i * KDIM + h * EPT + e] = (signed char)qv;
        }
      }
    }
    return;
  }
  if (b < 6144) {
    int i = (b - 2048) * 256 + tid;
    Lbf[i] = __float2bfloat16(label[i]);
    return;
  }
  int local = b - 6144;
  const bool first = local < 256;
  const float* src = first ? W0 : W1;
  __hip_bfloat16* dst = first ? W0t : W1t;
  int rem = local & 255;
  int c0 = (rem & 15) * 32, r0 = (rem >> 4) * 32;
  int tx = tid & 31, ty = tid >> 5;
  for (int i2 = ty; i2 < 32; i2 += 8) tile[i2][tx] = src[(size_t)(r0 + i2) * 512 + c0 + tx];
  __syncthreads();
  for (int i2 = ty; i2 < 32; i2 += 8)
    dst[(size_t)(c0 + i2) * 512 + r0 + tx] = __float2bfloat16(tile[tx][i2]);
}

// ------- 2) int8 gram, BK=128 (37 full + 64-tail) + T0t RIDER ---------------
__global__ __launch_bounds__(256) void gram_i8(const signed char* __restrict__ Y,
                                               float* __restrict__ S,
                                               const float* __restrict__ inv_s,
                                               const __hip_bfloat16* __restrict__ W0t,
                                               const __hip_bfloat16* __restrict__ Lbf,
                                               __hip_bfloat16* __restrict__ T0t) {
  __shared__ __attribute__((aligned(16))) char smem[32768];
  // XCD-locality remap: XCD k (id%8) owns col-tiles {k, k+8, k+16, k+24}
  const int id = blockIdx.x;
  const int bx = (id & 7) | (((id >> 3) & 3) << 3);
  const int by = id >> 5;
  const int row0 = by * 64, col0 = bx * 64;
  const int tid = threadIdx.x;
  const int lane = tid & 63;
  const int wn = tid >> 6;
  const int r = lane & 15, q = lane >> 4;

  if (col0 + 64 <= row0) {
    // ---- RIDER: T0t tile GEMM (dead gram slot), R23/R24/R25-proven ----
    const int d = (by * (by - 1)) / 2 + bx;  // 0..495 (bx < by)
    if (d >= 256) return;
    const int row0r = (d >> 5) * 64;  // [0,512)
    const int col0r = (d & 31) * 64;  // [0,2048)
    __hip_bfloat16* Asb = (__hip_bfloat16*)smem;             // [2][4096] bf16
    __hip_bfloat16* Bsb = (__hip_bfloat16*)(smem + 16384);   // [2][4096] bf16
    const int srow8 = tid >> 3;
    const int schunk8 = (tid & 7) ^ (srow8 & 7);
    f32x4 racc[4];
#pragma unroll
    for (int t = 0; t < 4; ++t) {
      f32x4 z = {0.f, 0.f, 0.f, 0.f};
      racc[t] = z;
    }
#define RSTAGE(bufi, k0)                                                                      \
  {                                                                                           \
    _Pragma("unroll") for (int it = 0; it < 2; ++it) {                                        \
      __builtin_amdgcn_global_load_lds(                                                       \
          (const __attribute__((address_space(1))) void*)(W0t + (size_t)(row0r + it * 32 + srow8) * 512 + \
                                                          (k0) + schunk8 * 8),                \
          (__attribute__((address_space(3))) void*)(Asb + (bufi)*4096 + (it * 256 + tid) * 8), 16, 0, 0); \
    }                                                                                         \
    _Pragma("unroll") for (int it = 0; it < 2; ++it) {                                        \
      __builtin_amdgcn_global_load_lds(                                                       \
          (const __attribute__((address_space(1))) void*)(Lbf + (size_t)(col0r + it * 32 + srow8) * 512 + \
                                                          (k0) + schunk8 * 8),                \
          (__attribute__((address_space(3))) void*)(Bsb + (bufi)*4096 + (it * 256 + tid) * 8), 16, 0, 0); \
    }                                                                                         \
  }
    RSTAGE(0, 0)
    for (int k = 0; k < 8; ++k) {
      __syncthreads();
      if (k + 1 < 8) RSTAGE((k + 1) & 1, (k + 1) * 64)
      const __hip_bfloat16* as = Asb + (k & 1) * 4096;
      const __hip_bfloat16* bs = Bsb + (k & 1) * 4096;
#pragma unroll
      for (int kk = 0; kk < 2; ++kk) {
        const int ch = ((kk * 4 + q) ^ (r & 7)) * 8;
        bf16x8 af[4];
#pragma unroll
        for (int t = 0; t < 4; ++t) af[t] = *(const bf16x8*)(as + (t * 16 + r) * 64 + ch);
        bf16x8 bfr = *(const bf16x8*)(bs + (wn * 16 + r) * 64 + ch);
#pragma unroll
        for (int t = 0; t < 4; ++t)
          racc[t] = __builtin_amdgcn_mfma_f32_16x16x32_bf16(af[t], bfr, racc[t], 0, 0, 0);
      }
    }
#undef RSTAGE
    const int gcr = col0r + wn * 16 + r;
#pragma unroll
    for (int t = 0; t < 4; ++t) {
      int gr0 = row0r + t * 16 + q * 4;
#pragma unroll
      for (int p = 0; p < 4; ++p)
        T0t[(size_t)(gr0 + p) * 2048 + gcr] = __float2bfloat16(racc[t][p]);
    }
    return;
  }

  // ---- gram main path: BK=128, double-buffered, proven-bf16 swizzle -------
  const bool do_mirror = (col0 > row0);
  signed char* As = (signed char*)smem;            // [2][8192] i8 (64 rows x 128B)
  signed char* Bs = (signed char*)(smem + 16384);  // [2][8192] i8

  i32x4 acc[4];
#pragma unroll
  for (int t = 0; t < 4; ++t) {
    i32x4 z = {0, 0, 0, 0};
    acc[t] = z;
  }
  constexpr int NF = 37;  // full BK=128 iterations (37*128 = 4736; tail 64)

  // BK=128 staging: 8KB/tile = 512 x 16B chunks, 2 per thread.
  // row = idx>>3, chunk-in-row c = idx&7, global chunk = c ^ (row&7)
  // (byte-identical addressing to the proven bf16 [64][128B] tile).
#define STAGE128(bufi, k0)                                                                     \
  {                                                                                            \
    _Pragma("unroll") for (int it = 0; it < 2; ++it) {                                         \
      const int idx = it * 256 + tid;                                                          \
      const int srw = idx >> 3;                                                                \
      const int scc = (idx & 7) ^ (srw & 7);                                                   \
      __builtin_amdgcn_global_load_lds(                                                        \
          (const __attribute__((address_space(1))) void*)(Y + (size_t)(row0 + srw) * KDIM +    \
                                                          (k0) + scc * 16),                    \
          (__attribute__((address_space(3))) void*)(As + (bufi)*8192 + idx * 16), 16, 0, 0);   \
    }                                                                                          \
    _Pragma("unroll") for (int it = 0; it < 2; ++it) {                                         \
      const int idx = it * 256 + tid;                                                          \
      const int srw = idx >> 3;                                                                \
      const int scc = (idx & 7) ^ (srw & 7);                                                   \
      __builtin_amdgcn_global_load_lds(                                                        \
          (const __attribute__((address_space(1))) void*)(Y + (size_t)(col0 + srw) * KDIM +    \
                                                          (k0) + scc * 16),                    \
          (__attribute__((address_space(3))) void*)(Bs + (bufi)*8192 + idx * 16), 16, 0, 0);   \
    }                                                                                          \
  }

  // 64-tail staging (R21/R22-proven [64][64B] pattern) into first 4KB of buf
#define STAGETAIL(bufi, k0)                                                                    \
  {                                                                                            \
    const int srw = tid >> 2;                                                                  \
    const int scc = (tid & 3) ^ ((srw >> 2) & 3);                                              \
    __builtin_amdgcn_global_load_lds(                                                          \
        (const __attribute__((address_space(1))) void*)(Y + (size_t)(row0 + srw) * KDIM +      \
                                                        (k0) + scc * 16),                      \
        (__attribute__((address_space(3))) void*)(As + (bufi)*8192 + tid * 16), 16, 0, 0);     \
    __builtin_amdgcn_global_load_lds(                                                          \
        (const __attribute__((address_space(1))) void*)(Y + (size_t)(col0 + srw) * KDIM +      \
                                                        (k0) + scc * 16),                      \
        (__attribute__((address_space(3))) void*)(Bs + (bufi)*8192 + tid * 16), 16, 0, 0);     \
  }

  STAGE128(0, 0)
  for (int k = 0; k <= NF; ++k) {
    __syncthreads();
    if (k + 1 < NF) {
      STAGE128((k + 1) & 1, (k + 1) * 128)
    } else if (k + 1 == NF) {
      STAGETAIL((k + 1) & 1, NF * 128)
    }
    if (k < NF) {
      const signed char* as = As + (k & 1) * 8192;
      const signed char* bs = Bs + (k & 1) * 8192;
#pragma unroll
      for (int kk = 0; kk < 2; ++kk) {
        const int ch = ((kk * 4 + q) ^ (r & 7)) * 16;  // proven-bf16 XOR, 16B units
        i32x4 bfrag = *(const i32x4*)(bs + (wn * 16 + r) * 128 + ch);
#pragma unroll
        for (int t = 0; t < 4; ++t) {
          i32x4 afrag = *(const i32x4*)(as + (t * 16 + r) * 128 + ch);
          acc[t] = __builtin_amdgcn_mfma_i32_16x16x64_i8(afrag, bfrag, acc[t], 0, 0, 0);
        }
      }
    } else {
      // tail: [64][64B] layout, R21/R22-proven compute pair
      const signed char* as = As + (k & 1) * 8192;
      const signed char* bs = Bs + (k & 1) * 8192;
      const int ch = (q ^ ((r >> 2) & 3)) * 16;
      i32x4 bfrag = *(const i32x4*)(bs + (wn * 16 + r) * 64 + ch);
#pragma unroll
      for (int t = 0; t < 4; ++t) {
        i32x4 afrag = *(const i32x4*)(as + (t * 16 + r) * 64 + ch);
        acc[t] = __builtin_amdgcn_mfma_i32_16x16x64_i8(afrag, bfrag, acc[t], 0, 0, 0);
      }
    }
  }
#undef STAGE128
#undef STAGETAIL
  // C/D layout: col = lane&15, row = (lane>>4)*4 + reg (shape-determined)
  const int gc = col0 + wn * 16 + r;
  const float sj = inv_s[gc];
#pragma unroll
  for (int t = 0; t < 4; ++t) {
    int gr0 = row0 + t * 16 + q * 4;
#pragma unroll
    for (int p = 0; p < 4; ++p) {
      float vv = (float)acc[t][p] * (inv_s[gr0 + p] * sj);
      S[(size_t)(gr0 + p) * L_DIM + gc] = vv;
      if (do_mirror) S[(size_t)gc * L_DIM + (gr0 + p)] = vv;
    }
  }
}

// ---------------- 2b) bf16 bt-GEMM (R17-proven, BK=64; used for T1t) --------
template <int BM, int BN, bool RELU, bool OUT_BF16>
__global__ __launch_bounds__(256) void gemm_bt(const __hip_bfloat16* __restrict__ A,
                                               const __hip_bfloat16* __restrict__ B,
                                               void* __restrict__ C0v,
                                               int M, int N, int K) {
  constexpr int WMG = BM / 64;
  constexpr int WNG = 4 / WMG;
  constexpr int NC = BN / (16 * WNG);
  const int row0 = blockIdx.y * BM, col0 = blockIdx.x * BN;
  __shared__ __attribute__((aligned(16))) __hip_bfloat16 As[2][BM * 64];
  __shared__ __attribute__((aligned(16))) __hip_bfloat16 Bs[2][BN * 64];
  const int tid = threadIdx.x;
  const int lane = tid & 63;
  const int wave = tid >> 6;
  const int wm = wave / WNG, wn = wave % WNG;
  const int r = lane & 15, q = lane >> 4;
  const int srow = tid >> 3;
  const int schunk = (tid & 7) ^ (srow & 7);

  f32x4 acc[4][NC];
#pragma unroll
  for (int a = 0; a < 4; ++a)
#pragma unroll
    for (int b = 0; b < NC; ++b) {
      f32x4 z = {0.f, 0.f, 0.f, 0.f};
      acc[a][b] = z;
    }

  const int niter = K >> 6;

#define STAGE(bufi, k0)                                                                       \
  {                                                                                           \
    _Pragma("unroll") for (int it = 0; it < BM / 32; ++it) {                                  \
      __builtin_amdgcn_global_load_lds(                                                       \
          (const __attribute__((address_space(1))) void*)(A + (size_t)(row0 + it * 32 + srow) * K + \
                                                          (k0) + schunk * 8),                 \
          (__attribute__((address_space(3))) void*)(&As[bufi][(it * 256 + tid) * 8]), 16, 0, 0); \
    }                                                                                         \
    _Pragma("unroll") for (int it = 0; it < BN / 32; ++it) {                                  \
      __builtin_amdgcn_global_load_lds(                                                       \
          (const __attribute__((address_space(1))) void*)(B + (size_t)(col0 + it * 32 + srow) * K + \
                                                          (k0) + schunk * 8),                 \
          (__attribute__((address_space(3))) void*)(&Bs[bufi][(it * 256 + tid) * 8]), 16, 0, 0); \
    }                                                                                         \
  }

  STAGE(0, 0)
  for (int k = 0; k < niter; ++k) {
    __syncthreads();
    if (k + 1 < niter) STAGE((k + 1) & 1, (k + 1) << 6)
    const __hip_bfloat16* as = As[k & 1];
    const __hip_bfloat16* bs = Bs[k & 1];
#pragma unroll
    for (int kk = 0; kk < 2; ++kk) {
      const int ch = ((kk * 4 + q) ^ (r & 7)) * 8;
      bf16x8 af[4], bfr[NC];
#pragma unroll
      for (int t = 0; t < 4; ++t)
        af[t] = *(const bf16x8*)(as + (wm * 64 + t * 16 + r) * 64 + ch);
#pragma unroll
      for (int c = 0; c < NC; ++c)
        bfr[c] = *(const bf16x8*)(bs + (wn * 16 * NC + c * 16 + r) * 64 + ch);
#pragma unroll
      for (int tm = 0; tm < 4; ++tm)
#pragma unroll
        for (int tn = 0; tn < NC; ++tn)
          acc[tm][tn] = __builtin_amdgcn_mfma_f32_16x16x32_bf16(af[tm], bfr[tn], acc[tm][tn], 0, 0, 0);
    }
  }
#undef STAGE
  // C/D layout: col = lane&15, row = (lane>>4)*4 + reg   [guide §3, m89-verified]
#pragma unroll
  for (int tm = 0; tm < 4; ++tm) {
    int gr0 = row0 + wm * 64 + tm * 16 + q * 4;
#pragma unroll
    for (int tn = 0; tn < NC; ++tn) {
      int gc = col0 + wn * 16 * NC + tn * 16 + r;
#pragma unroll
      for (int p = 0; p < 4; ++p) {
        float vv = acc[tm][tn][p];
        if (RELU) vv = fmaxf(vv, 0.f);
        if (OUT_BF16) {
          ((__hip_bfloat16*)C0v)[(size_t)(gr0 + p) * N + gc] = __float2bfloat16(vv);
        } else {
          ((float*)C0v)[(size_t)(gr0 + p) * N + gc] = vv;
        }
      }
    }
  }
}

// ------ 2c) fused split-K adj GEMM: 512 thr, 2 groups, in-block combine -----
// C = relu(A @ B^T): A [2048 x 2048] bf16, B [512 x 2048] bf16, C [2048 x 512].
template <bool OUT_BF16>
__global__ __launch_bounds__(512) void gemm_adj_fused(const __hip_bfloat16* __restrict__ A,
                                                      const __hip_bfloat16* __restrict__ B,
                                                      void* __restrict__ C0v) {
  constexpr int K = 2048, N = 512;
  __shared__ __attribute__((aligned(16))) __hip_bfloat16 sm[4][2][4096];  // 64KB
  const int tid = threadIdx.x;
  const int grp = tid >> 8;        // 0,1 -> K-half
  const int gtid = tid & 255;
  const int lane = tid & 63;
  const int wn = (tid >> 6) & 3;   // same for tid and tid+256
  const int r = lane & 15, q = lane >> 4;
  const int srow = gtid >> 3;
  const int schunk = (gtid & 7) ^ (srow & 7);
  const int row0 = blockIdx.y * 64, col0 = blockIdx.x * 64;
  const int kbeg = grp * 1024;
  __hip_bfloat16* As = &sm[grp * 2 + 0][0][0];
  __hip_bfloat16* Bs = &sm[grp * 2 + 1][0][0];

  f32x4 acc[4];
#pragma unroll
  for (int t = 0; t < 4; ++t) {
    f32x4 z = {0.f, 0.f, 0.f, 0.f};
    acc[t] = z;
  }

#define FSTAGE(bufi, k0)                                                                      \
  {                                                                                           \
    _Pragma("unroll") for (int it = 0; it < 2; ++it) {                                        \
      __builtin_amdgcn_global_load_lds(                                                       \
          (const __attribute__((address_space(1))) void*)(A + (size_t)(row0 + it * 32 + srow) * K + \
                                                          (k0) + schunk * 8),                 \
          (__attribute__((address_space(3))) void*)(As + (bufi)*4096 + (it * 256 + gtid) * 8), 16, 0, 0); \
    }                                                                                         \
    _Pragma("unroll") for (int it = 0; it < 2; ++it) {                                        \
      __builtin_amdgcn_global_load_lds(                                                       \
          (const __attribute__((address_space(1))) void*)(B + (size_t)(col0 + it * 32 + srow) * K + \
                                                          (k0) + schunk * 8),                 \
          (__attribute__((address_space(3))) void*)(Bs + (bufi)*4096 + (it * 256 + gtid) * 8), 16, 0, 0); \
    }                                                                                         \
  }

  FSTAGE(0, kbeg)
  for (int k = 0; k < 16; ++k) {
    __syncthreads();
    if (k + 1 < 16) FSTAGE((k + 1) & 1, kbeg + ((k + 1) << 6))
    const __hip_bfloat16* as = As + (k & 1) * 4096;
    const __hip_bfloat16* bs = Bs + (k & 1) * 4096;
#pragma unroll
    for (int kk = 0; kk < 2; ++kk) {
      const int ch = ((kk * 4 + q) ^ (r & 7)) * 8;
      bf16x8 af[4];
#pragma unroll
      for (int t = 0; t < 4; ++t) af[t] = *(const bf16x8*)(as + (t * 16 + r) * 64 + ch);
      bf16x8 bfr = *(const bf16x8*)(bs + (wn * 16 + r) * 64 + ch);
#pragma unroll
      for (int t = 0; t < 4; ++t)
        acc[t] = __builtin_amdgcn_mfma_f32_16x16x32_bf16(af[t], bfr, acc[t], 0, 0, 0);
    }
  }
#undef FSTAGE
  // in-block split-K combine (exact f32 add, == combiner kernels)
  __syncthreads();  // all compute done before group1 overwrites its As region
  float* F = (float*)&sm[2][0][0];  // 16KB, group1's As region
  if (grp == 1) {
#pragma unroll
    for (int tm = 0; tm < 4; ++tm)
#pragma unroll
      for (int p = 0; p < 4; ++p) F[gtid * 16 + tm * 4 + p] = acc[tm][p];
  }
  __syncthreads();
  if (grp == 0) {
#pragma unroll
    for (int tm = 0; tm < 4; ++tm) {
      int gr0 = row0 + tm * 16 + q * 4;
      int gc = col0 + wn * 16 + r;
#pragma unroll
      for (int p = 0; p < 4; ++p) {
        float vv = fmaxf(acc[tm][p] + F[gtid * 16 + tm * 4 + p], 0.f);
        if (OUT_BF16) {
          ((__hip_bfloat16*)C0v)[(size_t)(gr0 + p) * N + gc] = __float2bfloat16(vv);
        } else {
          ((float*)C0v)[(size_t)(gr0 + p) * N + gc] = vv;
        }
      }
    }
  }
}

// ------- 3) post: row->LDS, repair with W4-in-REGISTERS, softmax -> adj -----
__global__ __launch_bounds__(256) void post_kernel(const float* __restrict__ S,
                                                   __hip_bfloat16* __restrict__ adj,
                                                   const float* __restrict__ xpt,
                                                   const float* __restrict__ Wpt,
                                                   const float* __restrict__ rnorms) {
  __shared__ float rowv[L_DIM];  // 8KB: this row of S
  __shared__ int lq[1024];
  __shared__ int lcount;
  __shared__ float red[4];
  const int b = blockIdx.x;
  const int tid = threadIdx.x;
  if (tid == 0) lcount = 0;
  __syncthreads();
  const float* s = S + (size_t)b * L_DIM;
  // load row into LDS + queue borderline entries (FULL row — no mirrors needed;
  // row j repairs (j,i) itself with the bitwise-identical computation)
  for (int j0 = tid * 4; j0 < L_DIM; j0 += 1024) {
    float4 v = *(const float4*)(s + j0);
    *(float4*)(&rowv[j0]) = v;
    float vv[4] = {v.x, v.y, v.z, v.w};
#pragma unroll
    for (int u = 0; u < 4; ++u) {
      if (fabsf(vv[u] - 0.1f) < WINDOW) {
        int p = atomicAdd(&lcount, 1);
        if (p < 1024) lq[p] = j0 + u;
      }
    }
  }
  __syncthreads();
  const int n = min(lcount, 1024);
  if (n > 0) {
    const int lane = tid & 63;
    const int wave = tid >> 6;
    float xiv[5];
    float w4i[H_DIM][5];  // registers: w^4 * (1/n_i) — fully unrolled indices
    {
      const float* xi = xpt + b * EPT;
#pragma unroll
      for (int t = 0; t < 5; ++t) {
        int idx = lane + 64 * t;
        xiv[t] = idx < EPT ? xi[idx] : 0.f;
      }
#pragma unroll
      for (int h = 0; h < H_DIM; ++h) {
        float rni = rnorms[b * H_DIM + h];
#pragma unroll
        for (int t = 0; t < 5; ++t) {
          int idx = lane + 64 * t;
          float w = idx < EPT ? Wpt[h * EPT + idx] : 0.f;
          float w2 = w * w;
          w4i[h][t] = w2 * w2 * rni;
        }
      }
    }
    for (int k = wave; k < n; k += 4) {
      int j = lq[k];
      const float* xj = xpt + j * EPT;
      float pre[5];
#pragma unroll
      for (int t = 0; t < 5; ++t) {
        int idx = lane + 64 * t;
        pre[t] = idx < EPT ? xiv[t] * xj[idx] : 0.f;
      }
      float accv = 0.f;
#pragma unroll
      for (int h = 0; h < H_DIM; ++h) {
        float ph = 0.f;
#pragma unroll
        for (int t = 0; t < 5; ++t) ph += pre[t] * w4i[h][t];
        accv += ph * rnorms[j * H_DIM + h];  // broadcast load (uniform addr)
      }
#pragma unroll
      for (int o = 32; o >= 1; o >>= 1) accv += __shfl_xor(accv, o, 64);
      if (lane == 0) rowv[j] = accv * (1.f / 16.f);
    }
    __syncthreads();
  }
  // softmax from LDS (same math as proven post)
  float m = -1e30f;
  for (int j = tid; j < L_DIM; j += 256) {
    float v = rowv[j];
    if (v >= 0.1f && v > m) m = v;
  }
#pragma unroll
  for (int o = 32; o >= 1; o >>= 1) m = fmaxf(m, __shfl_xor(m, o, 64));
  if ((tid & 63) == 0) red[tid >> 6] = m;
  __syncthreads();
  m = fmaxf(fmaxf(red[0], red[1]), fmaxf(red[2], red[3]));
  float sum = 0.f;
  for (int j = tid; j < L_DIM; j += 256) {
    float v = rowv[j];
    if (v >= 0.1f) sum += __expf(v - m);
  }
#pragma unroll
  for (int o = 32; o >= 1; o >>= 1) sum += __shfl_xor(sum, o, 64);
  __syncthreads();
  if ((tid & 63) == 0) red[tid >> 6] = sum;
  __syncthreads();
  sum = red[0] + red[1] + red[2] + red[3];
  float inv = 1.f / sum;
  for (int j = tid; j < L_DIM; j += 256) {
    float v = rowv[j];
    float a = (v >= 0.1f) ? __expf(v - m) * inv : 0.f;
    adj[(size_t)b * L_DIM + j] = __float2bfloat16(a);
  }
}

extern "C" void kernel_launch(void* const* d_in, const int* in_sizes, int n_in, void* d_out,
                              int out_size, void* d_ws, size_t ws_size, hipStream_t stream) {
  const float* label = (const float*)d_in[0];  // [2048,512]
  const float* xpt = (const float*)d_in[1];    // [2048,300]
  const float* Wpt = (const float*)d_in[2];    // [16,300]
  const float* W0 = (const float*)d_in[3];     // [512,512]
  const float* W1 = (const float*)d_in[4];     // [512,512]
  float* out = (float*)d_out;                  // [2048,512]

  // ---- layout (peak 47.1MB; ws >= 53.4MB proven) ----
  char* ws = (char*)d_ws;
  signed char* Y = (signed char*)ws;                    // [0, 9,830,400) live thru gram
  float* S = (float*)(ws + 19660800);                   // [19,660,800, 36,438,016)
  float* rnorms = (float*)(ws + 36438016);              // 128KB -> ends 36,569,088
  float* inv_s = (float*)(ws + 44957696);               // 8KB -> ends 44,965,888
  __hip_bfloat16* Lbf = (__hip_bfloat16*)(ws + 44965888);  // 2MB -> ends 47,063,040
  __hip_bfloat16* adj = (__hip_bfloat16*)ws;            // [0, 8,388,608) after post (Y dead)
  // GCN temporaries above Y's region (disjoint from Y [0,9.83M)):
  __hip_bfloat16* W0t = (__hip_bfloat16*)(ws + 10485760);   // 0.5MB
  __hip_bfloat16* W1t = (__hip_bfloat16*)(ws + 11010048);   // 0.5MB
  __hip_bfloat16* T0t = (__hip_bfloat16*)(ws + 11534336);   // 2MB [512x2048]
  __hip_bfloat16* X1 = (__hip_bfloat16*)(ws + 13631488);    // 2MB [2048x512]
  __hip_bfloat16* T1t = (__hip_bfloat16*)(ws + 15728640);   // 2MB -> ends 17,825,792

  // 1) Y-quant rows (reciprocal norms) + label cast + W0/W1 transposes
  prep_kernel<<<6656, 256, 0, stream>>>(xpt, Wpt, label, W0, W1, Y, rnorms, inv_s, Lbf, W0t, W1t);
  // 2) gram BK=128 (triangle+mirror, XCD-swizzled) + T0t rider
  gram_i8<<<1024, 256, 0, stream>>>(Y, S, inv_s, W0t, Lbf, T0t);
  // 3) in-LDS borderline repair (W4 in registers) + softmax -> adj
  post_kernel<<<2048, 256, 0, stream>>>(S, adj, xpt, Wpt, rnorms);
  // 4) X1 = relu_bf16(adj @ T0t^T): fused in-block split-K=2
  gemm_adj_fused<true><<<dim3(8, 32), 512, 0, stream>>>(adj, T0t, X1);
  // 5) T1t = bf16(W1t @ X1^T)   [512 x 2048]
  gemm_bt<64, 64, false, true><<<dim3(32, 8), 256, 0, stream>>>(W1t, X1, T1t, 512, 2048, 512);
  // 6) out = relu_f32(adj @ T1t^T): fused in-block split-K=2
  gemm_adj_fused<false><<<dim3(8, 32), 512, 0, stream>>>(adj, T1t, out);
}